// Round 10
// baseline (484.113 us; speedup 1.0000x reference)
//
#include <hip/hip_runtime.h>
#include <math.h>

#define BB 16
#define SS 1024
#define NF 5
#define DD 64
#define HH 8
#define HDIM 8
#define NLAYER 2
#define FFD 128
#define NQ 8
#define QLAY 3
#define NC 3
#define NSWEEP 8
#define BHS_TOT (BB * HH * SS)   // 131072 = 1<<17

typedef __fp16 hf2 __attribute__((ext_vector_type(2)));
__device__ inline hf2 ash2(float f) { union { float f; hf2 h; } u; u.f = f; return u.h; }

// ---------------- embed + positional encoding ----------------
__global__ __launch_bounds__(64) void k_embed(const float* __restrict__ x,
                                              const float* __restrict__ Wemb,
                                              const float* __restrict__ bemb,
                                              float* __restrict__ h) {
    int bs = blockIdx.x;            // 0..B*S-1
    int s  = bs & (SS - 1);
    int d  = threadIdx.x;           // 0..63
    const float* xr = x + bs * NF;
    float acc = bemb[d];
#pragma unroll
    for (int f = 0; f < NF; ++f) acc += xr[f] * Wemb[f * DD + d];
    int i = d >> 1;
    float div = expf((float)(2 * i) * (-9.210340371976184f / 64.0f));
    float ang = (float)s * div;
    float pe = (d & 1) ? cosf(ang) : sinf(ang);
    h[bs * DD + d] = acc + pe;
}

// ---------------- fused q,k,v projection (4 rows/block; f16 packed out) -----
// qh: [BH,S][4 x h2]   q pairs over d, pre-scaled by 1/sqrt(8)
// kvh: per (bh,tp=t/2): 16 x h2 = { k_t0 d-pairs[4], k_t1 d-pairs[4], v[d]=(v_t0,v_t1)[8] }
__global__ __launch_bounds__(64) void k_qkv(const float* __restrict__ h,
                                            const float* __restrict__ Wq, const float* __restrict__ bq,
                                            const float* __restrict__ Wk, const float* __restrict__ bk,
                                            const float* __restrict__ Wv, const float* __restrict__ bv,
                                            hf2* __restrict__ qh, hf2* __restrict__ kvh, int l) {
    __shared__ float hrow[4][DD];
    int d   = threadIdx.x;
    int bs0 = blockIdx.x * 4;
#pragma unroll
    for (int r = 0; r < 4; ++r) hrow[r][d] = h[(bs0 + r) * DD + d];
    __syncthreads();
    const float* wq = Wq + l * DD * DD;
    const float* wk = Wk + l * DD * DD;
    const float* wv = Wv + l * DD * DD;
    float aq[4], ak[4], av[4];
    float bqv = bq[l * DD + d], bkv = bk[l * DD + d], bvv = bv[l * DD + d];
#pragma unroll
    for (int r = 0; r < 4; ++r) { aq[r] = bqv; ak[r] = bkv; av[r] = bvv; }
#pragma unroll 4
    for (int i = 0; i < DD; ++i) {
        float wqv = wq[i * DD + d], wkv = wk[i * DD + d], wvv = wv[i * DD + d];
#pragma unroll
        for (int r = 0; r < 4; ++r) {
            float hv = hrow[r][i];
            aq[r] += hv * wqv; ak[r] += hv * wkv; av[r] += hv * wvv;
        }
    }
    int hh = d >> 3, hd = d & 7;
    const float qs = 0.3535533906f;
    float aqp[4], akp[4];
#pragma unroll
    for (int r = 0; r < 4; ++r) { aqp[r] = __shfl_xor(aq[r], 1); akp[r] = __shfl_xor(ak[r], 1); }
    if ((hd & 1) == 0) {
#pragma unroll
        for (int r = 0; r < 4; ++r) {
            int bs = bs0 + r;
            int b = bs >> 10, s = bs & 1023;
            int bh = b * HH + hh;
            int bhs = (bh << 10) | s;
            qh[bhs * 4 + (hd >> 1)] = __builtin_amdgcn_cvt_pkrtz(aq[r] * qs, aqp[r] * qs);
            int tp = s >> 1, par = s & 1;
            kvh[(bh * 512 + tp) * 16 + par * 4 + (hd >> 1)] =
                __builtin_amdgcn_cvt_pkrtz(ak[r], akp[r]);
        }
    }
    // v pairs over t: rows (0,1) and (2,3) are consecutive s with even parity start
#pragma unroll
    for (int r = 0; r < 4; r += 2) {
        int bs = bs0 + r;
        int b = bs >> 10, s = bs & 1023;
        int bh = b * HH + hh;
        int tp = s >> 1;
        kvh[(bh * 512 + tp) * 16 + 8 + hd] = __builtin_amdgcn_cvt_pkrtz(av[r], av[r + 1]);
    }
}

// ---------------- attention: f16 dot2 math, 1 row/thread, t chunked ---------
__global__ __launch_bounds__(256) void k_attn(const hf2* __restrict__ qh,
                                              const float4* __restrict__ kvh4,
                                              float* __restrict__ Apart,   // [nch][BHS][8]
                                              float* __restrict__ lpart,   // [nch][BHS]
                                              int nch) {
    int bh  = blockIdx.x;             // 0..127
    int sg  = blockIdx.y & 3;
    int ch  = blockIdx.y >> 2;
    int tid = threadIdx.x;
    int s   = sg * 256 + tid;
    int tpc = 512 / nch;              // t-pairs per chunk
    const float4* kp = kvh4 + (size_t)(bh * 512 + ch * tpc) * 4;
    float4 qv = ((const float4*)qh)[(bh << 10) | s];
    hf2 q01 = ash2(qv.x), q23 = ash2(qv.y), q45 = ash2(qv.z), q67 = ash2(qv.w);
    hf2 one2 = __builtin_amdgcn_cvt_pkrtz(1.f, 1.f);
    float ls = 0.f;
    float A[8] = {0,0,0,0,0,0,0,0};
#pragma unroll 2
    for (int t = 0; t < tpc; ++t) {
        float4 f0 = kp[4*t], f1 = kp[4*t+1], f2 = kp[4*t+2], f3 = kp[4*t+3];
        float sc0 = __builtin_amdgcn_fdot2(q67, ash2(f0.w),
                    __builtin_amdgcn_fdot2(q45, ash2(f0.z),
                    __builtin_amdgcn_fdot2(q23, ash2(f0.y),
                    __builtin_amdgcn_fdot2(q01, ash2(f0.x), 0.f, false), false), false), false);
        float sc1 = __builtin_amdgcn_fdot2(q67, ash2(f1.w),
                    __builtin_amdgcn_fdot2(q45, ash2(f1.z),
                    __builtin_amdgcn_fdot2(q23, ash2(f1.y),
                    __builtin_amdgcn_fdot2(q01, ash2(f1.x), 0.f, false), false), false), false);
        float p0 = __expf(sc0), p1 = __expf(sc1);
        hf2 pp = __builtin_amdgcn_cvt_pkrtz(p0, p1);
        ls   = __builtin_amdgcn_fdot2(pp, one2,       ls,   false);
        A[0] = __builtin_amdgcn_fdot2(pp, ash2(f2.x), A[0], false);
        A[1] = __builtin_amdgcn_fdot2(pp, ash2(f2.y), A[1], false);
        A[2] = __builtin_amdgcn_fdot2(pp, ash2(f2.z), A[2], false);
        A[3] = __builtin_amdgcn_fdot2(pp, ash2(f2.w), A[3], false);
        A[4] = __builtin_amdgcn_fdot2(pp, ash2(f3.x), A[4], false);
        A[5] = __builtin_amdgcn_fdot2(pp, ash2(f3.y), A[5], false);
        A[6] = __builtin_amdgcn_fdot2(pp, ash2(f3.z), A[6], false);
        A[7] = __builtin_amdgcn_fdot2(pp, ash2(f3.w), A[7], false);
    }
    int bhs = (bh << 10) | s;
    float* arow = Apart + (((size_t)ch << 17) + bhs) * 8;
    ((float4*)arow)[0] = make_float4(A[0], A[1], A[2], A[3]);
    ((float4*)arow)[1] = make_float4(A[4], A[5], A[6], A[7]);
    lpart[((size_t)ch << 17) + bhs] = ls;
}

// ---------------- attention combine + O projection + residual + layernorm ----
__global__ __launch_bounds__(64) void k_projln(const float* __restrict__ Apart,
                                               const float* __restrict__ lpart,
                                               const float* __restrict__ Wo, const float* __restrict__ bo,
                                               const float* __restrict__ g, const float* __restrict__ bp,
                                               float* __restrict__ h, int l, int nch) {
    __shared__ float orow[4][DD];
    int d   = threadIdx.x;
    int bs0 = blockIdx.x * 4;
    int hh = d >> 3, hd = d & 7;
#pragma unroll
    for (int r = 0; r < 4; ++r) {
        int bs = bs0 + r;
        int b = bs >> 10, s = bs & 1023;
        int bhs = ((b * HH + hh) << 10) | s;
        float a = 0.f, lt = 0.f;
        for (int ch = 0; ch < nch; ++ch) {
            a  += Apart[(((size_t)ch << 17) + bhs) * 8 + hd];
            lt += lpart[((size_t)ch << 17) + bhs];
        }
        orow[r][d] = a / lt;
    }
    __syncthreads();
    const float* w = Wo + l * DD * DD;
    float bias = bo[l * DD + d];
    float acc[4] = {bias, bias, bias, bias};
#pragma unroll 4
    for (int i = 0; i < DD; ++i) {
        float wv = w[i * DD + d];
        acc[0] += orow[0][i]*wv; acc[1] += orow[1][i]*wv;
        acc[2] += orow[2][i]*wv; acc[3] += orow[3][i]*wv;
    }
    float gg = g[l * DD + d], bb = bp[l * DD + d];
#pragma unroll
    for (int r = 0; r < 4; ++r) {
        int bs = bs0 + r;
        float a = acc[r] + h[bs * DD + d];
        float sum = a;
        for (int off = 32; off; off >>= 1) sum += __shfl_xor(sum, off);
        float mean = sum * (1.f / 64.f);
        float dx = a - mean;
        float vs = dx * dx;
        for (int off = 32; off; off >>= 1) vs += __shfl_xor(vs, off);
        float rstd = rsqrtf(vs * (1.f / 64.f) + 1e-5f);
        h[bs * DD + d] = dx * rstd * gg + bb;
    }
}

// ---------------- FFN layer 1 (relu), 4 rows/block ----------------
__global__ __launch_bounds__(128) void k_ffn1(const float* __restrict__ h,
                                              const float* __restrict__ W, const float* __restrict__ bias,
                                              float* __restrict__ ff, int l) {
    __shared__ float hrow[4][DD];
    int f   = threadIdx.x;
    int bs0 = blockIdx.x * 4;
#pragma unroll
    for (int e = f; e < 4 * DD; e += 128) ((float*)hrow)[e] = h[bs0 * DD + e];
    __syncthreads();
    const float* w = W + l * DD * FFD;
    float bv = bias[l * FFD + f];
    float acc[4] = {bv, bv, bv, bv};
#pragma unroll 4
    for (int i = 0; i < DD; ++i) {
        float wv = w[i * FFD + f];
        acc[0] += hrow[0][i]*wv; acc[1] += hrow[1][i]*wv;
        acc[2] += hrow[2][i]*wv; acc[3] += hrow[3][i]*wv;
    }
#pragma unroll
    for (int r = 0; r < 4; ++r) ff[(bs0 + r) * FFD + f] = fmaxf(acc[r], 0.f);
}

// ---------------- FFN layer 2 + residual + layernorm, 4 rows/block ----------
__global__ __launch_bounds__(64) void k_ffn2ln(const float* __restrict__ ff,
                                               const float* __restrict__ W, const float* __restrict__ bias,
                                               const float* __restrict__ g, const float* __restrict__ bp,
                                               float* __restrict__ h, int l) {
    __shared__ float frow[4][FFD];
    int d   = threadIdx.x;
    int bs0 = blockIdx.x * 4;
#pragma unroll
    for (int e = d; e < 4 * FFD; e += 64) ((float*)frow)[e] = ff[bs0 * FFD + e];
    __syncthreads();
    const float* w = W + l * FFD * DD;
    float bv = bias[l * DD + d];
    float acc[4] = {bv, bv, bv, bv};
#pragma unroll 4
    for (int i = 0; i < FFD; ++i) {
        float wv = w[i * DD + d];
        acc[0] += frow[0][i]*wv; acc[1] += frow[1][i]*wv;
        acc[2] += frow[2][i]*wv; acc[3] += frow[3][i]*wv;
    }
    float gg = g[l * DD + d], bb = bp[l * DD + d];
#pragma unroll
    for (int r = 0; r < 4; ++r) {
        int bs = bs0 + r;
        float a = acc[r] + h[bs * DD + d];
        float sum = a;
        for (int off = 32; off; off >>= 1) sum += __shfl_xor(sum, off);
        float mean = sum * (1.f / 64.f);
        float dx = a - mean;
        float vs = dx * dx;
        for (int off = 32; off; off >>= 1) vs += __shfl_xor(vs, off);
        float rstd = rsqrtf(vs * (1.f / 64.f) + 1e-5f);
        h[bs * DD + d] = dx * rstd * gg + bb;
    }
}

// ---------------- mean pool over sequence (8-way split) ----------------
__global__ __launch_bounds__(64) void k_pool(const float* __restrict__ h, float* __restrict__ pp) {
    int b = blockIdx.x, c = blockIdx.y, d = threadIdx.x;
    const float* hp = h + (b * SS + c * 128) * DD + d;
    float acc = 0.f;
#pragma unroll 8
    for (int s = 0; s < 128; ++s) acc += hp[s * DD];
    pp[(b * 8 + c) * DD + d] = acc;
}

// ---------------- MLP head -> angles ----------------
__global__ __launch_bounds__(64) void k_head(const float* __restrict__ pp,
                                             const float* __restrict__ Wp1, const float* __restrict__ bp1,
                                             const float* __restrict__ Wp2, const float* __restrict__ bp2,
                                             float* __restrict__ angles) {
    __shared__ float pool_s[DD];
    __shared__ float hid[32];
    int b = blockIdx.x; int t = threadIdx.x;
    float acc = 0.f;
#pragma unroll
    for (int c = 0; c < 8; ++c) acc += pp[(b * 8 + c) * DD + t];
    pool_s[t] = acc * (1.f / 1024.f);
    __syncthreads();
    if (t < 32) {
        float a = bp1[t];
        for (int i = 0; i < DD; ++i) a += pool_s[i] * Wp1[i * 32 + t];
        hid[t] = fmaxf(a, 0.f);
    }
    __syncthreads();
    if (t < NQ) {
        float a = bp2[t];
        for (int j = 0; j < 32; ++j) a += hid[j] * Wp2[j * NQ + t];
        angles[b * NQ + t] = tanhf(a) * 3.14159265358979f;
    }
}

// ---------------- quantum circuit + Z-exps; writes psi for eigensolver ------
// One wave per batch. Amplitude index i = (r<<6)|lane; wire w <-> bit (7-w).
__global__ __launch_bounds__(64) void k_qcirc(const float* __restrict__ angles,
                                              const float* __restrict__ qw,
                                              float* __restrict__ out,
                                              float2* __restrict__ psig) {
    int b = blockIdx.x; int L = threadIdx.x;
    float ar[4], ai[4];
#pragma unroll
    for (int r = 0; r < 4; ++r) { ar[r] = 0.f; ai[r] = 0.f; }
    if (L == 0) ar[0] = 1.f;

    const float* ang = angles + b * NQ;
    for (int l = 0; l < QLAY; ++l) {
#pragma unroll
        for (int w = 0; w < NQ; ++w) {
            int p = 7 - w;
            float half = 0.5f * ang[w];
            float c = cosf(half), s = sinf(half);
            if (p == 7) {
#pragma unroll
                for (int lo = 0; lo < 2; ++lo) {
                    int hi = lo + 2;
                    float r0=ar[lo], m0=ai[lo], r1=ar[hi], m1=ai[hi];
                    ar[lo] = c*r0 + s*m1;  ai[lo] = c*m0 - s*r1;
                    ar[hi] = c*r1 + s*m0;  ai[hi] = c*m1 - s*r0;
                }
            } else if (p == 6) {
#pragma unroll
                for (int base = 0; base < 4; base += 2) {
                    int lo = base, hi = base + 1;
                    float r0=ar[lo], m0=ai[lo], r1=ar[hi], m1=ai[hi];
                    ar[lo] = c*r0 + s*m1;  ai[lo] = c*m0 - s*r1;
                    ar[hi] = c*r1 + s*m0;  ai[hi] = c*m1 - s*r0;
                }
            } else {
                int mask = 1 << p;
#pragma unroll
                for (int r = 0; r < 4; ++r) {
                    float pre = __shfl_xor(ar[r], mask);
                    float pim = __shfl_xor(ai[r], mask);
                    float nr = c*ar[r] + s*pim;
                    float ni = c*ai[r] - s*pre;
                    ar[r] = nr; ai[r] = ni;
                }
            }
        }
#pragma unroll
        for (int w = 0; w < NQ; ++w) {
            const float* p3 = qw + (l * NQ + w) * 3;
            float phi = p3[0], th = p3[1], om = p3[2];
            float ct = cosf(0.5f * th), st = sinf(0.5f * th);
            float al = 0.5f * (phi + om), be = 0.5f * (phi - om);
            float ca = cosf(al), sa = sinf(al), cb = cosf(be), sb = sinf(be);
            float u00r =  ct * ca, u00i = -ct * sa;
            float u01r = -st * cb, u01i = -st * sb;
            float u10r =  st * cb, u10i = -st * sb;
            float u11r =  ct * ca, u11i =  ct * sa;
            int p = 7 - w;
            if (p >= 6) {
#pragma unroll
                for (int pi_ = 0; pi_ < 2; ++pi_) {
                    int lo = (p == 7) ? pi_ : pi_ * 2;
                    int hi = (p == 7) ? pi_ + 2 : pi_ * 2 + 1;
                    float r0=ar[lo], m0=ai[lo], r1=ar[hi], m1=ai[hi];
                    ar[lo] = u00r*r0 - u00i*m0 + u01r*r1 - u01i*m1;
                    ai[lo] = u00r*m0 + u00i*r0 + u01r*m1 + u01i*r1;
                    ar[hi] = u10r*r0 - u10i*m0 + u11r*r1 - u11i*m1;
                    ai[hi] = u10r*m0 + u10i*r0 + u11r*m1 + u11i*r1;
                }
            } else {
                int mask = 1 << p;
                int bit = (L >> p) & 1;
                float car = bit ? u11r : u00r, cai = bit ? u11i : u00i;
                float cpr = bit ? u10r : u01r, cpi = bit ? u10i : u01i;
#pragma unroll
                for (int r = 0; r < 4; ++r) {
                    float pre = __shfl_xor(ar[r], mask);
                    float pim = __shfl_xor(ai[r], mask);
                    float nr = car*ar[r] - cai*ai[r] + cpr*pre - cpi*pim;
                    float ni = car*ai[r] + cai*ar[r] + cpr*pim + cpi*pre;
                    ar[r] = nr; ai[r] = ni;
                }
            }
        }
        { float t0=ar[2]; ar[2]=ar[3]; ar[3]=t0; t0=ai[2]; ai[2]=ai[3]; ai[3]=t0; }
        ar[1]=__shfl_xor(ar[1],32); ai[1]=__shfl_xor(ai[1],32);
        ar[3]=__shfl_xor(ar[3],32); ai[3]=__shfl_xor(ai[3],32);
#pragma unroll
        for (int w = 2; w <= 6; ++w) {
            int pc = 7 - w, pt = 6 - w;
            int tm = 1 << pt;
            bool ctrl = (L >> pc) & 1;
#pragma unroll
            for (int r = 0; r < 4; ++r) {
                float swr = __shfl_xor(ar[r], tm);
                float swi = __shfl_xor(ai[r], tm);
                ar[r] = ctrl ? swr : ar[r];
                ai[r] = ctrl ? swi : ai[r];
            }
        }
        {
            bool ctrl = L & 1;
            float n0r = ctrl ? ar[2] : ar[0], n2r = ctrl ? ar[0] : ar[2];
            float n0i = ctrl ? ai[2] : ai[0], n2i = ctrl ? ai[0] : ai[2];
            float n1r = ctrl ? ar[3] : ar[1], n3r = ctrl ? ar[1] : ar[3];
            float n1i = ctrl ? ai[3] : ai[1], n3i = ctrl ? ai[1] : ai[3];
            ar[0]=n0r; ar[1]=n1r; ar[2]=n2r; ar[3]=n3r;
            ai[0]=n0i; ai[1]=n1i; ai[2]=n2i; ai[3]=n3i;
        }
    }

    // ---- <Z_w>, w=0..2 ----
    {
        float p0 = ar[0]*ar[0]+ai[0]*ai[0];
        float p1 = ar[1]*ar[1]+ai[1]*ai[1];
        float p2 = ar[2]*ar[2]+ai[2]*ai[2];
        float p3 = ar[3]*ar[3]+ai[3]*ai[3];
        float z0 = p0 + p1 - p2 - p3;
        float z1 = p0 - p1 + p2 - p3;
        float zs = p0 + p1 + p2 + p3;
        float z2 = (L & 32) ? -zs : zs;
#pragma unroll
        for (int off = 1; off < 64; off <<= 1) {
            z0 += __shfl_xor(z0, off);
            z1 += __shfl_xor(z1, off);
            z2 += __shfl_xor(z2, off);
        }
        if (L == 0) {
            out[b * NC + 0] = z0;
            out[b * NC + 1] = z1;
            out[b * NC + 2] = z2;
        }
    }

    // ---- write psi: linear index (r<<6)|L already equals row*16+col ----
#pragma unroll
    for (int r = 0; r < 4; ++r) psig[(b << 8) | (r << 6) | L] = make_float2(ar[r], ai[r]);
}

// ---------------- eigensolver: one-sided Jacobi, column-per-lane ------------
// 4 blocks x 64 lanes; lane = (batch-in-block<<4)|column. Entire 16-elem column
// in registers; partner column via shfl; dots lane-local (no reductions).
// Per-column phases are irrelevant (rho = M M^H invariant), so both pair
// members use the same select-free update with their own (d,e,tau).
__global__ __launch_bounds__(64) void k_qeig(const float2* __restrict__ psig,
                                             float* __restrict__ out) {
    __shared__ float2 Ps[4 * 256];
    int g = blockIdx.x;               // 0..3
    int L = threadIdx.x;
    const float2* src = psig + g * 4 * 256;
    for (int i = L; i < 1024; i += 64) Ps[i] = src[i];
    __syncthreads();
    int bl = L >> 4;                  // batch within block
    int c  = L & 15;                  // my column
    float gr[16], gi[16];
#pragma unroll
    for (int k = 0; k < 16; ++k) {
        float2 t = Ps[bl * 256 + k * 16 + c];
        gr[k] = t.x; gi[k] = t.y;
    }

    for (int sweep = 0; sweep < NSWEEP; ++sweep) {
        for (int rd = 0; rd < 15; ++rd) {
            int q;
            if (c == 15) q = rd;
            else {
                int u = c - rd; if (u < 0) u += 15;
                if (u == 0) q = 15;
                else { q = rd + 15 - u; if (q >= 15) q -= 15; }
            }
            int plane = (L & 48) | q;
            float pgr[16], pgi[16];
#pragma unroll
            for (int k = 0; k < 16; ++k) {
                pgr[k] = __shfl(gr[k], plane);
                pgi[k] = __shfl(gi[k], plane);
            }
            float alm = 0.f, d = 0.f, e = 0.f;
#pragma unroll
            for (int k = 0; k < 16; ++k) {
                alm += gr[k]*gr[k] + gi[k]*gi[k];
                d   += gr[k]*pgr[k] + gi[k]*pgi[k];   // Re(mine^H partner)
                e   += gr[k]*pgi[k] - gi[k]*pgr[k];   // Im(mine^H partner)
            }
            float bep = __shfl(alm, plane);           // |partner|^2
            float g2 = d*d + e*e;
            float cth = 1.f, sth = 0.f, cph = 1.f, sph = 0.f;
            if (g2 > 1e-26f) {
                float gn = sqrtf(g2);
                float ginv = 1.f / gn;
                cph = d * ginv; sph = -e * ginv;       // conj(gamma)/|gamma|
                float tau = (alm - bep) * (0.5f * ginv);
                float t = ((tau >= 0.f) ? 1.f : -1.f) / (fabsf(tau) + sqrtf(1.f + tau*tau));
                cth = rsqrtf(1.f + t*t);
                sth = t * cth;
            }
#pragma unroll
            for (int k = 0; k < 16; ++k) {
                float er = cph*pgr[k] - sph*pgi[k];
                float ei = cph*pgi[k] + sph*pgr[k];
                gr[k] = cth * gr[k] + sth * er;
                gi[k] = cth * gi[k] + sth * ei;
            }
        }
    }

    float lam = 0.f;
#pragma unroll
    for (int k = 0; k < 16; ++k) lam += gr[k]*gr[k] + gi[k]*gi[k];
    float ev = fminf(fmaxf(lam, 1e-10f), 1.0f);
    float term = -ev * logf(ev);
#pragma unroll
    for (int off = 1; off <= 8; off <<= 1) term += __shfl_xor(term, off);
    if (c == 0) out[BB * NC + g * 4 + bl] = term;
}

extern "C" void kernel_launch(void* const* d_in, const int* in_sizes, int n_in,
                              void* d_out, int out_size, void* d_ws, size_t ws_size,
                              hipStream_t stream) {
    const float* x    = (const float*)d_in[0];
    const float* Wemb = (const float*)d_in[1];
    const float* bemb = (const float*)d_in[2];
    const float* Wq   = (const float*)d_in[3];
    const float* bq   = (const float*)d_in[4];
    const float* Wk   = (const float*)d_in[5];
    const float* bk   = (const float*)d_in[6];
    const float* Wv   = (const float*)d_in[7];
    const float* bv   = (const float*)d_in[8];
    const float* Wo   = (const float*)d_in[9];
    const float* bo   = (const float*)d_in[10];
    const float* ln1g = (const float*)d_in[11];
    const float* ln1b = (const float*)d_in[12];
    const float* ln2g = (const float*)d_in[13];
    const float* ln2b = (const float*)d_in[14];
    const float* Wf1  = (const float*)d_in[15];
    const float* bf1  = (const float*)d_in[16];
    const float* Wf2  = (const float*)d_in[17];
    const float* bf2  = (const float*)d_in[18];
    const float* Wp1  = (const float*)d_in[19];
    const float* bp1  = (const float*)d_in[20];
    const float* Wp2  = (const float*)d_in[21];
    const float* bp2  = (const float*)d_in[22];
    const float* qwts = (const float*)d_in[23];
    float* out = (float*)d_out;

    const size_t M = 1u << 20;           // 1M floats = B*S*D
    // float-unit sizes: h=1M, qh=0.5M, kvh=1M, ff=2M, Apart=nch*M, lpart=nch*BHS
    auto needF = [&](int nch) {
        return (size_t)(4.5 * M) + (size_t)nch * M + (size_t)nch * BHS_TOT + BB * 8 * DD + 16384;
    };
    int nch = (ws_size >= needF(4) * sizeof(float)) ? 4 : 2;

    float* ws     = (float*)d_ws;
    float* h      = ws;                               // 1M
    hf2*   qh     = (hf2*)(ws + M);                   // 0.5M floats
    hf2*   kvh    = (hf2*)(ws + M + M / 2);           // 1M floats
    float* ff     = ws + (M * 5) / 2;                 // 2M
    float* Apart  = ws + (M * 9) / 2;                 // nch*M
    float* lpart  = Apart + (size_t)nch * M;          // nch*BHS_TOT
    float* pp     = lpart + (size_t)nch * BHS_TOT;    // [16][8][64]
    float* angls  = pp + BB * 8 * DD;                 // [B,NQ]
    float2* psig  = (float2*)(angls + 256);           // [16][256] float2 = 8K floats

    k_embed<<<BB * SS, 64, 0, stream>>>(x, Wemb, bemb, h);
    for (int l = 0; l < NLAYER; ++l) {
        k_qkv<<<BB * SS / 4, 64, 0, stream>>>(h, Wq, bq, Wk, bk, Wv, bv, qh, kvh, l);
        k_attn<<<dim3(BB * HH, 4 * nch), 256, 0, stream>>>(qh, (const float4*)kvh, Apart, lpart, nch);
        k_projln<<<BB * SS / 4, 64, 0, stream>>>(Apart, lpart, Wo, bo, ln1g, ln1b, h, l, nch);
        k_ffn1<<<BB * SS / 4, 128, 0, stream>>>(h, Wf1, bf1, ff, l);
        k_ffn2ln<<<BB * SS / 4, 64, 0, stream>>>(ff, Wf2, bf2, ln2g, ln2b, h, l);
    }
    k_pool<<<dim3(BB, 8), 64, 0, stream>>>(h, pp);
    k_head<<<BB, 64, 0, stream>>>(pp, Wp1, bp1, Wp2, bp2, angls);
    k_qcirc<<<BB, 64, 0, stream>>>(angls, qwts, out, psig);
    k_qeig<<<4, 64, 0, stream>>>(psig, out);
}

// Round 11
// 462.306 us; speedup vs baseline: 1.0472x; 1.0472x over previous
//
#include <hip/hip_runtime.h>
#include <math.h>

#define BB 16
#define SS 1024
#define NF 5
#define DD 64
#define HH 8
#define HDIM 8
#define NLAYER 2
#define FFD 128
#define NQ 8
#define QLAY 3
#define NC 3
#define NSWEEP 8
#define BHS_TOT (BB * HH * SS)   // 131072 = 1<<17

typedef __fp16 hf2 __attribute__((ext_vector_type(2)));
__device__ inline hf2 ash2(float f) { union { float f; hf2 h; } u; u.f = f; return u.h; }

// ---------------- embed + positional encoding ----------------
__global__ __launch_bounds__(64) void k_embed(const float* __restrict__ x,
                                              const float* __restrict__ Wemb,
                                              const float* __restrict__ bemb,
                                              float* __restrict__ h) {
    int bs = blockIdx.x;            // 0..B*S-1
    int s  = bs & (SS - 1);
    int d  = threadIdx.x;           // 0..63
    const float* xr = x + bs * NF;
    float acc = bemb[d];
#pragma unroll
    for (int f = 0; f < NF; ++f) acc += xr[f] * Wemb[f * DD + d];
    int i = d >> 1;
    float div = expf((float)(2 * i) * (-9.210340371976184f / 64.0f));
    float ang = (float)s * div;
    float pe = (d & 1) ? cosf(ang) : sinf(ang);
    h[bs * DD + d] = acc + pe;
}

// ---------------- fused q,k,v projection (4 rows/block; f16 packed out) -----
__global__ __launch_bounds__(64) void k_qkv(const float* __restrict__ h,
                                            const float* __restrict__ Wq, const float* __restrict__ bq,
                                            const float* __restrict__ Wk, const float* __restrict__ bk,
                                            const float* __restrict__ Wv, const float* __restrict__ bv,
                                            hf2* __restrict__ qh, hf2* __restrict__ kvh, int l) {
    __shared__ float hrow[4][DD];
    int d   = threadIdx.x;
    int bs0 = blockIdx.x * 4;
#pragma unroll
    for (int r = 0; r < 4; ++r) hrow[r][d] = h[(bs0 + r) * DD + d];
    __syncthreads();
    const float* wq = Wq + l * DD * DD;
    const float* wk = Wk + l * DD * DD;
    const float* wv = Wv + l * DD * DD;
    float aq[4], ak[4], av[4];
    float bqv = bq[l * DD + d], bkv = bk[l * DD + d], bvv = bv[l * DD + d];
#pragma unroll
    for (int r = 0; r < 4; ++r) { aq[r] = bqv; ak[r] = bkv; av[r] = bvv; }
#pragma unroll 4
    for (int i = 0; i < DD; ++i) {
        float wqv = wq[i * DD + d], wkv = wk[i * DD + d], wvv = wv[i * DD + d];
#pragma unroll
        for (int r = 0; r < 4; ++r) {
            float hv = hrow[r][i];
            aq[r] += hv * wqv; ak[r] += hv * wkv; av[r] += hv * wvv;
        }
    }
    int hh = d >> 3, hd = d & 7;
    const float qs = 0.3535533906f;
    float aqp[4], akp[4];
#pragma unroll
    for (int r = 0; r < 4; ++r) { aqp[r] = __shfl_xor(aq[r], 1); akp[r] = __shfl_xor(ak[r], 1); }
    if ((hd & 1) == 0) {
#pragma unroll
        for (int r = 0; r < 4; ++r) {
            int bs = bs0 + r;
            int b = bs >> 10, s = bs & 1023;
            int bh = b * HH + hh;
            int bhs = (bh << 10) | s;
            qh[bhs * 4 + (hd >> 1)] = __builtin_amdgcn_cvt_pkrtz(aq[r] * qs, aqp[r] * qs);
            int tp = s >> 1, par = s & 1;
            kvh[(bh * 512 + tp) * 16 + par * 4 + (hd >> 1)] =
                __builtin_amdgcn_cvt_pkrtz(ak[r], akp[r]);
        }
    }
#pragma unroll
    for (int r = 0; r < 4; r += 2) {
        int bs = bs0 + r;
        int b = bs >> 10, s = bs & 1023;
        int bh = b * HH + hh;
        int tp = s >> 1;
        kvh[(bh * 512 + tp) * 16 + 8 + hd] = __builtin_amdgcn_cvt_pkrtz(av[r], av[r + 1]);
    }
}

// ---------------- attention: f16 dot2 math, 1 row/thread, t chunked ---------
__global__ __launch_bounds__(256) void k_attn(const hf2* __restrict__ qh,
                                              const float4* __restrict__ kvh4,
                                              float* __restrict__ Apart,   // [nch][BHS][8]
                                              float* __restrict__ lpart,   // [nch][BHS]
                                              int nch) {
    int bh  = blockIdx.x;             // 0..127
    int sg  = blockIdx.y & 3;
    int ch  = blockIdx.y >> 2;
    int tid = threadIdx.x;
    int s   = sg * 256 + tid;
    int tpc = 512 / nch;              // t-pairs per chunk
    const float4* kp = kvh4 + (size_t)(bh * 512 + ch * tpc) * 4;
    float4 qv = ((const float4*)qh)[(bh << 10) | s];
    hf2 q01 = ash2(qv.x), q23 = ash2(qv.y), q45 = ash2(qv.z), q67 = ash2(qv.w);
    hf2 one2 = __builtin_amdgcn_cvt_pkrtz(1.f, 1.f);
    float ls = 0.f;
    float A[8] = {0,0,0,0,0,0,0,0};
#pragma unroll 2
    for (int t = 0; t < tpc; ++t) {
        float4 f0 = kp[4*t], f1 = kp[4*t+1], f2 = kp[4*t+2], f3 = kp[4*t+3];
        float sc0 = __builtin_amdgcn_fdot2(q67, ash2(f0.w),
                    __builtin_amdgcn_fdot2(q45, ash2(f0.z),
                    __builtin_amdgcn_fdot2(q23, ash2(f0.y),
                    __builtin_amdgcn_fdot2(q01, ash2(f0.x), 0.f, false), false), false), false);
        float sc1 = __builtin_amdgcn_fdot2(q67, ash2(f1.w),
                    __builtin_amdgcn_fdot2(q45, ash2(f1.z),
                    __builtin_amdgcn_fdot2(q23, ash2(f1.y),
                    __builtin_amdgcn_fdot2(q01, ash2(f1.x), 0.f, false), false), false), false);
        float p0 = __expf(sc0), p1 = __expf(sc1);
        hf2 pp = __builtin_amdgcn_cvt_pkrtz(p0, p1);
        ls   = __builtin_amdgcn_fdot2(pp, one2,       ls,   false);
        A[0] = __builtin_amdgcn_fdot2(pp, ash2(f2.x), A[0], false);
        A[1] = __builtin_amdgcn_fdot2(pp, ash2(f2.y), A[1], false);
        A[2] = __builtin_amdgcn_fdot2(pp, ash2(f2.z), A[2], false);
        A[3] = __builtin_amdgcn_fdot2(pp, ash2(f2.w), A[3], false);
        A[4] = __builtin_amdgcn_fdot2(pp, ash2(f3.x), A[4], false);
        A[5] = __builtin_amdgcn_fdot2(pp, ash2(f3.y), A[5], false);
        A[6] = __builtin_amdgcn_fdot2(pp, ash2(f3.z), A[6], false);
        A[7] = __builtin_amdgcn_fdot2(pp, ash2(f3.w), A[7], false);
    }
    int bhs = (bh << 10) | s;
    float* arow = Apart + (((size_t)ch << 17) + bhs) * 8;
    ((float4*)arow)[0] = make_float4(A[0], A[1], A[2], A[3]);
    ((float4*)arow)[1] = make_float4(A[4], A[5], A[6], A[7]);
    lpart[((size_t)ch << 17) + bhs] = ls;
}

// ---------------- attention combine + O projection + residual + layernorm ----
__global__ __launch_bounds__(64) void k_projln(const float* __restrict__ Apart,
                                               const float* __restrict__ lpart,
                                               const float* __restrict__ Wo, const float* __restrict__ bo,
                                               const float* __restrict__ g, const float* __restrict__ bp,
                                               float* __restrict__ h, int l, int nch) {
    __shared__ float orow[4][DD];
    int d   = threadIdx.x;
    int bs0 = blockIdx.x * 4;
    int hh = d >> 3, hd = d & 7;
#pragma unroll
    for (int r = 0; r < 4; ++r) {
        int bs = bs0 + r;
        int b = bs >> 10, s = bs & 1023;
        int bhs = ((b * HH + hh) << 10) | s;
        float a = 0.f, lt = 0.f;
        for (int ch = 0; ch < nch; ++ch) {
            a  += Apart[(((size_t)ch << 17) + bhs) * 8 + hd];
            lt += lpart[((size_t)ch << 17) + bhs];
        }
        orow[r][d] = a / lt;
    }
    __syncthreads();
    const float* w = Wo + l * DD * DD;
    float bias = bo[l * DD + d];
    float acc[4] = {bias, bias, bias, bias};
#pragma unroll 4
    for (int i = 0; i < DD; ++i) {
        float wv = w[i * DD + d];
        acc[0] += orow[0][i]*wv; acc[1] += orow[1][i]*wv;
        acc[2] += orow[2][i]*wv; acc[3] += orow[3][i]*wv;
    }
    float gg = g[l * DD + d], bb = bp[l * DD + d];
#pragma unroll
    for (int r = 0; r < 4; ++r) {
        int bs = bs0 + r;
        float a = acc[r] + h[bs * DD + d];
        float sum = a;
        for (int off = 32; off; off >>= 1) sum += __shfl_xor(sum, off);
        float mean = sum * (1.f / 64.f);
        float dx = a - mean;
        float vs = dx * dx;
        for (int off = 32; off; off >>= 1) vs += __shfl_xor(vs, off);
        float rstd = rsqrtf(vs * (1.f / 64.f) + 1e-5f);
        h[bs * DD + d] = dx * rstd * gg + bb;
    }
}

// ---------------- FFN layer 1 (relu), 4 rows/block ----------------
__global__ __launch_bounds__(128) void k_ffn1(const float* __restrict__ h,
                                              const float* __restrict__ W, const float* __restrict__ bias,
                                              float* __restrict__ ff, int l) {
    __shared__ float hrow[4][DD];
    int f   = threadIdx.x;
    int bs0 = blockIdx.x * 4;
#pragma unroll
    for (int e = f; e < 4 * DD; e += 128) ((float*)hrow)[e] = h[bs0 * DD + e];
    __syncthreads();
    const float* w = W + l * DD * FFD;
    float bv = bias[l * FFD + f];
    float acc[4] = {bv, bv, bv, bv};
#pragma unroll 4
    for (int i = 0; i < DD; ++i) {
        float wv = w[i * FFD + f];
        acc[0] += hrow[0][i]*wv; acc[1] += hrow[1][i]*wv;
        acc[2] += hrow[2][i]*wv; acc[3] += hrow[3][i]*wv;
    }
#pragma unroll
    for (int r = 0; r < 4; ++r) ff[(bs0 + r) * FFD + f] = fmaxf(acc[r], 0.f);
}

// ---------------- FFN layer 2 + residual + layernorm, 4 rows/block ----------
__global__ __launch_bounds__(64) void k_ffn2ln(const float* __restrict__ ff,
                                               const float* __restrict__ W, const float* __restrict__ bias,
                                               const float* __restrict__ g, const float* __restrict__ bp,
                                               float* __restrict__ h, int l) {
    __shared__ float frow[4][FFD];
    int d   = threadIdx.x;
    int bs0 = blockIdx.x * 4;
#pragma unroll
    for (int e = d; e < 4 * FFD; e += 64) ((float*)frow)[e] = ff[bs0 * FFD + e];
    __syncthreads();
    const float* w = W + l * FFD * DD;
    float bv = bias[l * DD + d];
    float acc[4] = {bv, bv, bv, bv};
#pragma unroll 4
    for (int i = 0; i < FFD; ++i) {
        float wv = w[i * DD + d];
        acc[0] += frow[0][i]*wv; acc[1] += frow[1][i]*wv;
        acc[2] += frow[2][i]*wv; acc[3] += frow[3][i]*wv;
    }
    float gg = g[l * DD + d], bb = bp[l * DD + d];
#pragma unroll
    for (int r = 0; r < 4; ++r) {
        int bs = bs0 + r;
        float a = acc[r] + h[bs * DD + d];
        float sum = a;
        for (int off = 32; off; off >>= 1) sum += __shfl_xor(sum, off);
        float mean = sum * (1.f / 64.f);
        float dx = a - mean;
        float vs = dx * dx;
        for (int off = 32; off; off >>= 1) vs += __shfl_xor(vs, off);
        float rstd = rsqrtf(vs * (1.f / 64.f) + 1e-5f);
        h[bs * DD + d] = dx * rstd * gg + bb;
    }
}

// ---------------- mean pool over sequence (8-way split) ----------------
__global__ __launch_bounds__(64) void k_pool(const float* __restrict__ h, float* __restrict__ pp) {
    int b = blockIdx.x, c = blockIdx.y, d = threadIdx.x;
    const float* hp = h + (b * SS + c * 128) * DD + d;
    float acc = 0.f;
#pragma unroll 8
    for (int s = 0; s < 128; ++s) acc += hp[s * DD];
    pp[(b * 8 + c) * DD + d] = acc;
}

// ---------------- MLP head -> angles ----------------
__global__ __launch_bounds__(64) void k_head(const float* __restrict__ pp,
                                             const float* __restrict__ Wp1, const float* __restrict__ bp1,
                                             const float* __restrict__ Wp2, const float* __restrict__ bp2,
                                             float* __restrict__ angles) {
    __shared__ float pool_s[DD];
    __shared__ float hid[32];
    int b = blockIdx.x; int t = threadIdx.x;
    float acc = 0.f;
#pragma unroll
    for (int c = 0; c < 8; ++c) acc += pp[(b * 8 + c) * DD + t];
    pool_s[t] = acc * (1.f / 1024.f);
    __syncthreads();
    if (t < 32) {
        float a = bp1[t];
        for (int i = 0; i < DD; ++i) a += pool_s[i] * Wp1[i * 32 + t];
        hid[t] = fmaxf(a, 0.f);
    }
    __syncthreads();
    if (t < NQ) {
        float a = bp2[t];
        for (int j = 0; j < 32; ++j) a += hid[j] * Wp2[j * NQ + t];
        angles[b * NQ + t] = tanhf(a) * 3.14159265358979f;
    }
}

// ---------------- quantum circuit + Z-exps; writes psi for eigensolver ------
__global__ __launch_bounds__(64) void k_qcirc(const float* __restrict__ angles,
                                              const float* __restrict__ qw,
                                              float* __restrict__ out,
                                              float2* __restrict__ psig) {
    int b = blockIdx.x; int L = threadIdx.x;
    float ar[4], ai[4];
#pragma unroll
    for (int r = 0; r < 4; ++r) { ar[r] = 0.f; ai[r] = 0.f; }
    if (L == 0) ar[0] = 1.f;

    const float* ang = angles + b * NQ;
    for (int l = 0; l < QLAY; ++l) {
#pragma unroll
        for (int w = 0; w < NQ; ++w) {
            int p = 7 - w;
            float half = 0.5f * ang[w];
            float c = cosf(half), s = sinf(half);
            if (p == 7) {
#pragma unroll
                for (int lo = 0; lo < 2; ++lo) {
                    int hi = lo + 2;
                    float r0=ar[lo], m0=ai[lo], r1=ar[hi], m1=ai[hi];
                    ar[lo] = c*r0 + s*m1;  ai[lo] = c*m0 - s*r1;
                    ar[hi] = c*r1 + s*m0;  ai[hi] = c*m1 - s*r0;
                }
            } else if (p == 6) {
#pragma unroll
                for (int base = 0; base < 4; base += 2) {
                    int lo = base, hi = base + 1;
                    float r0=ar[lo], m0=ai[lo], r1=ar[hi], m1=ai[hi];
                    ar[lo] = c*r0 + s*m1;  ai[lo] = c*m0 - s*r1;
                    ar[hi] = c*r1 + s*m0;  ai[hi] = c*m1 - s*r0;
                }
            } else {
                int mask = 1 << p;
#pragma unroll
                for (int r = 0; r < 4; ++r) {
                    float pre = __shfl_xor(ar[r], mask);
                    float pim = __shfl_xor(ai[r], mask);
                    float nr = c*ar[r] + s*pim;
                    float ni = c*ai[r] - s*pre;
                    ar[r] = nr; ai[r] = ni;
                }
            }
        }
#pragma unroll
        for (int w = 0; w < NQ; ++w) {
            const float* p3 = qw + (l * NQ + w) * 3;
            float phi = p3[0], th = p3[1], om = p3[2];
            float ct = cosf(0.5f * th), st = sinf(0.5f * th);
            float al = 0.5f * (phi + om), be = 0.5f * (phi - om);
            float ca = cosf(al), sa = sinf(al), cb = cosf(be), sb = sinf(be);
            float u00r =  ct * ca, u00i = -ct * sa;
            float u01r = -st * cb, u01i = -st * sb;
            float u10r =  st * cb, u10i = -st * sb;
            float u11r =  ct * ca, u11i =  ct * sa;
            int p = 7 - w;
            if (p >= 6) {
#pragma unroll
                for (int pi_ = 0; pi_ < 2; ++pi_) {
                    int lo = (p == 7) ? pi_ : pi_ * 2;
                    int hi = (p == 7) ? pi_ + 2 : pi_ * 2 + 1;
                    float r0=ar[lo], m0=ai[lo], r1=ar[hi], m1=ai[hi];
                    ar[lo] = u00r*r0 - u00i*m0 + u01r*r1 - u01i*m1;
                    ai[lo] = u00r*m0 + u00i*r0 + u01r*m1 + u01i*r1;
                    ar[hi] = u10r*r0 - u10i*m0 + u11r*r1 - u11i*m1;
                    ai[hi] = u10r*m0 + u10i*r0 + u11r*m1 + u11i*r1;
                }
            } else {
                int mask = 1 << p;
                int bit = (L >> p) & 1;
                float car = bit ? u11r : u00r, cai = bit ? u11i : u00i;
                float cpr = bit ? u10r : u01r, cpi = bit ? u10i : u01i;
#pragma unroll
                for (int r = 0; r < 4; ++r) {
                    float pre = __shfl_xor(ar[r], mask);
                    float pim = __shfl_xor(ai[r], mask);
                    float nr = car*ar[r] - cai*ai[r] + cpr*pre - cpi*pim;
                    float ni = car*ai[r] + cai*ar[r] + cpr*pim + cpi*pre;
                    ar[r] = nr; ai[r] = ni;
                }
            }
        }
        { float t0=ar[2]; ar[2]=ar[3]; ar[3]=t0; t0=ai[2]; ai[2]=ai[3]; ai[3]=t0; }
        ar[1]=__shfl_xor(ar[1],32); ai[1]=__shfl_xor(ai[1],32);
        ar[3]=__shfl_xor(ar[3],32); ai[3]=__shfl_xor(ai[3],32);
#pragma unroll
        for (int w = 2; w <= 6; ++w) {
            int pc = 7 - w, pt = 6 - w;
            int tm = 1 << pt;
            bool ctrl = (L >> pc) & 1;
#pragma unroll
            for (int r = 0; r < 4; ++r) {
                float swr = __shfl_xor(ar[r], tm);
                float swi = __shfl_xor(ai[r], tm);
                ar[r] = ctrl ? swr : ar[r];
                ai[r] = ctrl ? swi : ai[r];
            }
        }
        {
            bool ctrl = L & 1;
            float n0r = ctrl ? ar[2] : ar[0], n2r = ctrl ? ar[0] : ar[2];
            float n0i = ctrl ? ai[2] : ai[0], n2i = ctrl ? ai[0] : ai[2];
            float n1r = ctrl ? ar[3] : ar[1], n3r = ctrl ? ar[1] : ar[3];
            float n1i = ctrl ? ai[3] : ai[1], n3i = ctrl ? ai[1] : ai[3];
            ar[0]=n0r; ar[1]=n1r; ar[2]=n2r; ar[3]=n3r;
            ai[0]=n0i; ai[1]=n1i; ai[2]=n2i; ai[3]=n3i;
        }
    }

    {
        float p0 = ar[0]*ar[0]+ai[0]*ai[0];
        float p1 = ar[1]*ar[1]+ai[1]*ai[1];
        float p2 = ar[2]*ar[2]+ai[2]*ai[2];
        float p3 = ar[3]*ar[3]+ai[3]*ai[3];
        float z0 = p0 + p1 - p2 - p3;
        float z1 = p0 - p1 + p2 - p3;
        float zs = p0 + p1 + p2 + p3;
        float z2 = (L & 32) ? -zs : zs;
#pragma unroll
        for (int off = 1; off < 64; off <<= 1) {
            z0 += __shfl_xor(z0, off);
            z1 += __shfl_xor(z1, off);
            z2 += __shfl_xor(z2, off);
        }
        if (L == 0) {
            out[b * NC + 0] = z0;
            out[b * NC + 1] = z1;
            out[b * NC + 2] = z2;
        }
    }

#pragma unroll
    for (int r = 0; r < 4; ++r) psig[(b << 8) | (r << 6) | L] = make_float2(ar[r], ai[r]);
}

// ---------------- eigensolver: one-sided Jacobi, column-per-lane, LDS mirror
// 4 blocks x 1 wave; lane = (batch-in-block<<4)|column. Column lives in
// registers AND in LDS (stride-9 float4 to de-pattern banks). Partner column
// fetched via 8 ds_read_b128 (one wait), partner norm via 1 shfl. Phase-folded
// select-free update (per-column phases don't affect rho = M M^H).
__global__ __launch_bounds__(64) void k_qeig(const float2* __restrict__ psig,
                                             float* __restrict__ out) {
    __shared__ float4 Ps[64 * 9];     // 64 columns, stride 9 float4 (8 used + 1 pad)
    int g = blockIdx.x;               // 0..3
    int L = threadIdx.x;
    int bl = L >> 4;                  // batch within block
    int c  = L & 15;                  // my column
    const float2* src = psig + ((g * 4 + bl) << 8);
    float gr[16], gi[16];
#pragma unroll
    for (int k = 0; k < 16; ++k) {
        float2 t = src[k * 16 + c];
        gr[k] = t.x; gi[k] = t.y;
    }
    float4* myP = Ps + L * 9;
#pragma unroll
    for (int k = 0; k < 8; ++k)
        myP[k] = make_float4(gr[2*k], gi[2*k], gr[2*k+1], gi[2*k+1]);
    // single wave: DS ops execute in program order; no barrier needed

    for (int sweep = 0; sweep < NSWEEP; ++sweep) {
        for (int rd = 0; rd < 15; ++rd) {
            int q;
            if (c == 15) q = rd;
            else {
                int u = c - rd; if (u < 0) u += 15;
                if (u == 0) q = 15;
                else { q = rd + 15 - u; if (q >= 15) q -= 15; }
            }
            int plane = (L & 48) | q;
            const float4* pp4 = Ps + plane * 9;
            float4 pc[8];
#pragma unroll
            for (int k = 0; k < 8; ++k) pc[k] = pp4[k];
            float alm = 0.f, d = 0.f, e = 0.f;
#pragma unroll
            for (int k = 0; k < 8; ++k) {
                float g0r = gr[2*k], g0i = gi[2*k], g1r = gr[2*k+1], g1i = gi[2*k+1];
                alm += g0r*g0r + g0i*g0i + g1r*g1r + g1i*g1i;
                d   += g0r*pc[k].x + g0i*pc[k].y + g1r*pc[k].z + g1i*pc[k].w;
                e   += g0r*pc[k].y - g0i*pc[k].x + g1r*pc[k].w - g1i*pc[k].z;
            }
            float bep = __shfl(alm, plane);           // |partner|^2
            float g2 = d*d + e*e;
            float cth = 1.f, sth = 0.f, cph = 1.f, sph = 0.f;
            if (g2 > 1e-26f) {
                float gn = sqrtf(g2);
                float ginv = 1.f / gn;
                cph = d * ginv; sph = -e * ginv;       // conj(gamma)/|gamma|
                float tau = (alm - bep) * (0.5f * ginv);
                float t = ((tau >= 0.f) ? 1.f : -1.f) / (fabsf(tau) + sqrtf(1.f + tau*tau));
                cth = rsqrtf(1.f + t*t);
                sth = t * cth;
            }
#pragma unroll
            for (int k = 0; k < 8; ++k) {
                float er0 = cph*pc[k].x - sph*pc[k].y;
                float ei0 = cph*pc[k].y + sph*pc[k].x;
                float er1 = cph*pc[k].z - sph*pc[k].w;
                float ei1 = cph*pc[k].w + sph*pc[k].z;
                gr[2*k]   = cth * gr[2*k]   + sth * er0;
                gi[2*k]   = cth * gi[2*k]   + sth * ei0;
                gr[2*k+1] = cth * gr[2*k+1] + sth * er1;
                gi[2*k+1] = cth * gi[2*k+1] + sth * ei1;
            }
#pragma unroll
            for (int k = 0; k < 8; ++k)
                myP[k] = make_float4(gr[2*k], gi[2*k], gr[2*k+1], gi[2*k+1]);
        }
    }

    float lam = 0.f;
#pragma unroll
    for (int k = 0; k < 16; ++k) lam += gr[k]*gr[k] + gi[k]*gi[k];
    float ev = fminf(fmaxf(lam, 1e-10f), 1.0f);
    float term = -ev * logf(ev);
#pragma unroll
    for (int off = 1; off <= 8; off <<= 1) term += __shfl_xor(term, off);
    if (c == 0) out[BB * NC + g * 4 + bl] = term;
}

extern "C" void kernel_launch(void* const* d_in, const int* in_sizes, int n_in,
                              void* d_out, int out_size, void* d_ws, size_t ws_size,
                              hipStream_t stream) {
    const float* x    = (const float*)d_in[0];
    const float* Wemb = (const float*)d_in[1];
    const float* bemb = (const float*)d_in[2];
    const float* Wq   = (const float*)d_in[3];
    const float* bq   = (const float*)d_in[4];
    const float* Wk   = (const float*)d_in[5];
    const float* bk   = (const float*)d_in[6];
    const float* Wv   = (const float*)d_in[7];
    const float* bv   = (const float*)d_in[8];
    const float* Wo   = (const float*)d_in[9];
    const float* bo   = (const float*)d_in[10];
    const float* ln1g = (const float*)d_in[11];
    const float* ln1b = (const float*)d_in[12];
    const float* ln2g = (const float*)d_in[13];
    const float* ln2b = (const float*)d_in[14];
    const float* Wf1  = (const float*)d_in[15];
    const float* bf1  = (const float*)d_in[16];
    const float* Wf2  = (const float*)d_in[17];
    const float* bf2  = (const float*)d_in[18];
    const float* Wp1  = (const float*)d_in[19];
    const float* bp1  = (const float*)d_in[20];
    const float* Wp2  = (const float*)d_in[21];
    const float* bp2  = (const float*)d_in[22];
    const float* qwts = (const float*)d_in[23];
    float* out = (float*)d_out;

    const size_t M = 1u << 20;           // 1M floats = B*S*D
    auto needF = [&](int nch) {
        return (size_t)(4.5 * M) + (size_t)nch * M + (size_t)nch * BHS_TOT + BB * 8 * DD + 16384;
    };
    int nch = (ws_size >= needF(4) * sizeof(float)) ? 4 : 2;

    float* ws     = (float*)d_ws;
    float* h      = ws;                               // 1M
    hf2*   qh     = (hf2*)(ws + M);                   // 0.5M floats
    hf2*   kvh    = (hf2*)(ws + M + M / 2);           // 1M floats
    float* ff     = ws + (M * 5) / 2;                 // 2M
    float* Apart  = ws + (M * 9) / 2;                 // nch*M
    float* lpart  = Apart + (size_t)nch * M;          // nch*BHS_TOT
    float* pp     = lpart + (size_t)nch * BHS_TOT;    // [16][8][64]
    float* angls  = pp + BB * 8 * DD;                 // [B,NQ]
    float2* psig  = (float2*)(angls + 256);           // [16][256] float2

    k_embed<<<BB * SS, 64, 0, stream>>>(x, Wemb, bemb, h);
    for (int l = 0; l < NLAYER; ++l) {
        k_qkv<<<BB * SS / 4, 64, 0, stream>>>(h, Wq, bq, Wk, bk, Wv, bv, qh, kvh, l);
        k_attn<<<dim3(BB * HH, 4 * nch), 256, 0, stream>>>(qh, (const float4*)kvh, Apart, lpart, nch);
        k_projln<<<BB * SS / 4, 64, 0, stream>>>(Apart, lpart, Wo, bo, ln1g, ln1b, h, l, nch);
        k_ffn1<<<BB * SS / 4, 128, 0, stream>>>(h, Wf1, bf1, ff, l);
        k_ffn2ln<<<BB * SS / 4, 64, 0, stream>>>(ff, Wf2, bf2, ln2g, ln2b, h, l);
    }
    k_pool<<<dim3(BB, 8), 64, 0, stream>>>(h, pp);
    k_head<<<BB, 64, 0, stream>>>(pp, Wp1, bp1, Wp2, bp2, angls);
    k_qcirc<<<BB, 64, 0, stream>>>(angls, qwts, out, psig);
    k_qeig<<<4, 64, 0, stream>>>(psig, out);
}

// Round 12
// 458.392 us; speedup vs baseline: 1.0561x; 1.0085x over previous
//
#include <hip/hip_runtime.h>
#include <math.h>

#define BB 16
#define SS 1024
#define NF 5
#define DD 64
#define HH 8
#define HDIM 8
#define NLAYER 2
#define FFD 128
#define NQ 8
#define QLAY 3
#define NC 3
#define NSWEEP 8
#define BHS_TOT (BB * HH * SS)   // 131072 = 1<<17

typedef __fp16 hf2 __attribute__((ext_vector_type(2)));
__device__ inline hf2 ash2(float f) { union { float f; hf2 h; } u; u.f = f; return u.h; }

// ---------------- embed + positional encoding ----------------
__global__ __launch_bounds__(64) void k_embed(const float* __restrict__ x,
                                              const float* __restrict__ Wemb,
                                              const float* __restrict__ bemb,
                                              float* __restrict__ h) {
    int bs = blockIdx.x;            // 0..B*S-1
    int s  = bs & (SS - 1);
    int d  = threadIdx.x;           // 0..63
    const float* xr = x + bs * NF;
    float acc = bemb[d];
#pragma unroll
    for (int f = 0; f < NF; ++f) acc += xr[f] * Wemb[f * DD + d];
    int i = d >> 1;
    float div = expf((float)(2 * i) * (-9.210340371976184f / 64.0f));
    float ang = (float)s * div;
    float pe = (d & 1) ? cosf(ang) : sinf(ang);
    h[bs * DD + d] = acc + pe;
}

// ---------------- fused q,k,v projection (4 rows/block; f16 packed out) -----
__global__ __launch_bounds__(64) void k_qkv(const float* __restrict__ h,
                                            const float* __restrict__ Wq, const float* __restrict__ bq,
                                            const float* __restrict__ Wk, const float* __restrict__ bk,
                                            const float* __restrict__ Wv, const float* __restrict__ bv,
                                            hf2* __restrict__ qh, hf2* __restrict__ kvh, int l) {
    __shared__ float hrow[4][DD];
    int d   = threadIdx.x;
    int bs0 = blockIdx.x * 4;
#pragma unroll
    for (int r = 0; r < 4; ++r) hrow[r][d] = h[(bs0 + r) * DD + d];
    __syncthreads();
    const float* wq = Wq + l * DD * DD;
    const float* wk = Wk + l * DD * DD;
    const float* wv = Wv + l * DD * DD;
    float aq[4], ak[4], av[4];
    float bqv = bq[l * DD + d], bkv = bk[l * DD + d], bvv = bv[l * DD + d];
#pragma unroll
    for (int r = 0; r < 4; ++r) { aq[r] = bqv; ak[r] = bkv; av[r] = bvv; }
#pragma unroll 4
    for (int i = 0; i < DD; ++i) {
        float wqv = wq[i * DD + d], wkv = wk[i * DD + d], wvv = wv[i * DD + d];
#pragma unroll
        for (int r = 0; r < 4; ++r) {
            float hv = hrow[r][i];
            aq[r] += hv * wqv; ak[r] += hv * wkv; av[r] += hv * wvv;
        }
    }
    int hh = d >> 3, hd = d & 7;
    const float qs = 0.3535533906f;
    float aqp[4], akp[4];
#pragma unroll
    for (int r = 0; r < 4; ++r) { aqp[r] = __shfl_xor(aq[r], 1); akp[r] = __shfl_xor(ak[r], 1); }
    if ((hd & 1) == 0) {
#pragma unroll
        for (int r = 0; r < 4; ++r) {
            int bs = bs0 + r;
            int b = bs >> 10, s = bs & 1023;
            int bh = b * HH + hh;
            int bhs = (bh << 10) | s;
            qh[bhs * 4 + (hd >> 1)] = __builtin_amdgcn_cvt_pkrtz(aq[r] * qs, aqp[r] * qs);
            int tp = s >> 1, par = s & 1;
            kvh[(bh * 512 + tp) * 16 + par * 4 + (hd >> 1)] =
                __builtin_amdgcn_cvt_pkrtz(ak[r], akp[r]);
        }
    }
#pragma unroll
    for (int r = 0; r < 4; r += 2) {
        int bs = bs0 + r;
        int b = bs >> 10, s = bs & 1023;
        int bh = b * HH + hh;
        int tp = s >> 1;
        kvh[(bh * 512 + tp) * 16 + 8 + hd] = __builtin_amdgcn_cvt_pkrtz(av[r], av[r + 1]);
    }
}

// ---------------- attention: f16 dot2 math, 1 row/thread, t chunked ---------
__global__ __launch_bounds__(256) void k_attn(const hf2* __restrict__ qh,
                                              const float4* __restrict__ kvh4,
                                              float* __restrict__ Apart,   // [nch][BHS][8]
                                              float* __restrict__ lpart,   // [nch][BHS]
                                              int nch) {
    int bh  = blockIdx.x;             // 0..127
    int sg  = blockIdx.y & 3;
    int ch  = blockIdx.y >> 2;
    int tid = threadIdx.x;
    int s   = sg * 256 + tid;
    int tpc = 512 / nch;              // t-pairs per chunk
    const float4* kp = kvh4 + (size_t)(bh * 512 + ch * tpc) * 4;
    float4 qv = ((const float4*)qh)[(bh << 10) | s];
    hf2 q01 = ash2(qv.x), q23 = ash2(qv.y), q45 = ash2(qv.z), q67 = ash2(qv.w);
    hf2 one2 = __builtin_amdgcn_cvt_pkrtz(1.f, 1.f);
    float ls = 0.f;
    float A[8] = {0,0,0,0,0,0,0,0};
#pragma unroll 2
    for (int t = 0; t < tpc; ++t) {
        float4 f0 = kp[4*t], f1 = kp[4*t+1], f2 = kp[4*t+2], f3 = kp[4*t+3];
        float sc0 = __builtin_amdgcn_fdot2(q67, ash2(f0.w),
                    __builtin_amdgcn_fdot2(q45, ash2(f0.z),
                    __builtin_amdgcn_fdot2(q23, ash2(f0.y),
                    __builtin_amdgcn_fdot2(q01, ash2(f0.x), 0.f, false), false), false), false);
        float sc1 = __builtin_amdgcn_fdot2(q67, ash2(f1.w),
                    __builtin_amdgcn_fdot2(q45, ash2(f1.z),
                    __builtin_amdgcn_fdot2(q23, ash2(f1.y),
                    __builtin_amdgcn_fdot2(q01, ash2(f1.x), 0.f, false), false), false), false);
        float p0 = __expf(sc0), p1 = __expf(sc1);
        hf2 pp = __builtin_amdgcn_cvt_pkrtz(p0, p1);
        ls   = __builtin_amdgcn_fdot2(pp, one2,       ls,   false);
        A[0] = __builtin_amdgcn_fdot2(pp, ash2(f2.x), A[0], false);
        A[1] = __builtin_amdgcn_fdot2(pp, ash2(f2.y), A[1], false);
        A[2] = __builtin_amdgcn_fdot2(pp, ash2(f2.z), A[2], false);
        A[3] = __builtin_amdgcn_fdot2(pp, ash2(f2.w), A[3], false);
        A[4] = __builtin_amdgcn_fdot2(pp, ash2(f3.x), A[4], false);
        A[5] = __builtin_amdgcn_fdot2(pp, ash2(f3.y), A[5], false);
        A[6] = __builtin_amdgcn_fdot2(pp, ash2(f3.z), A[6], false);
        A[7] = __builtin_amdgcn_fdot2(pp, ash2(f3.w), A[7], false);
    }
    int bhs = (bh << 10) | s;
    float* arow = Apart + (((size_t)ch << 17) + bhs) * 8;
    ((float4*)arow)[0] = make_float4(A[0], A[1], A[2], A[3]);
    ((float4*)arow)[1] = make_float4(A[4], A[5], A[6], A[7]);
    lpart[((size_t)ch << 17) + bhs] = ls;
}

// ---------------- attention combine + O projection + residual + layernorm ----
__global__ __launch_bounds__(64) void k_projln(const float* __restrict__ Apart,
                                               const float* __restrict__ lpart,
                                               const float* __restrict__ Wo, const float* __restrict__ bo,
                                               const float* __restrict__ g, const float* __restrict__ bp,
                                               float* __restrict__ h, int l, int nch) {
    __shared__ float orow[4][DD];
    int d   = threadIdx.x;
    int bs0 = blockIdx.x * 4;
    int hh = d >> 3, hd = d & 7;
#pragma unroll
    for (int r = 0; r < 4; ++r) {
        int bs = bs0 + r;
        int b = bs >> 10, s = bs & 1023;
        int bhs = ((b * HH + hh) << 10) | s;
        float a = 0.f, lt = 0.f;
        for (int ch = 0; ch < nch; ++ch) {
            a  += Apart[(((size_t)ch << 17) + bhs) * 8 + hd];
            lt += lpart[((size_t)ch << 17) + bhs];
        }
        orow[r][d] = a / lt;
    }
    __syncthreads();
    const float* w = Wo + l * DD * DD;
    float bias = bo[l * DD + d];
    float acc[4] = {bias, bias, bias, bias};
#pragma unroll 4
    for (int i = 0; i < DD; ++i) {
        float wv = w[i * DD + d];
        acc[0] += orow[0][i]*wv; acc[1] += orow[1][i]*wv;
        acc[2] += orow[2][i]*wv; acc[3] += orow[3][i]*wv;
    }
    float gg = g[l * DD + d], bb = bp[l * DD + d];
#pragma unroll
    for (int r = 0; r < 4; ++r) {
        int bs = bs0 + r;
        float a = acc[r] + h[bs * DD + d];
        float sum = a;
        for (int off = 32; off; off >>= 1) sum += __shfl_xor(sum, off);
        float mean = sum * (1.f / 64.f);
        float dx = a - mean;
        float vs = dx * dx;
        for (int off = 32; off; off >>= 1) vs += __shfl_xor(vs, off);
        float rstd = rsqrtf(vs * (1.f / 64.f) + 1e-5f);
        h[bs * DD + d] = dx * rstd * gg + bb;
    }
}

// ---------------- FFN layer 1 (relu), 4 rows/block ----------------
__global__ __launch_bounds__(128) void k_ffn1(const float* __restrict__ h,
                                              const float* __restrict__ W, const float* __restrict__ bias,
                                              float* __restrict__ ff, int l) {
    __shared__ float hrow[4][DD];
    int f   = threadIdx.x;
    int bs0 = blockIdx.x * 4;
#pragma unroll
    for (int e = f; e < 4 * DD; e += 128) ((float*)hrow)[e] = h[bs0 * DD + e];
    __syncthreads();
    const float* w = W + l * DD * FFD;
    float bv = bias[l * FFD + f];
    float acc[4] = {bv, bv, bv, bv};
#pragma unroll 4
    for (int i = 0; i < DD; ++i) {
        float wv = w[i * FFD + f];
        acc[0] += hrow[0][i]*wv; acc[1] += hrow[1][i]*wv;
        acc[2] += hrow[2][i]*wv; acc[3] += hrow[3][i]*wv;
    }
#pragma unroll
    for (int r = 0; r < 4; ++r) ff[(bs0 + r) * FFD + f] = fmaxf(acc[r], 0.f);
}

// ---------------- FFN layer 2 + residual + layernorm, 4 rows/block ----------
__global__ __launch_bounds__(64) void k_ffn2ln(const float* __restrict__ ff,
                                               const float* __restrict__ W, const float* __restrict__ bias,
                                               const float* __restrict__ g, const float* __restrict__ bp,
                                               float* __restrict__ h, int l) {
    __shared__ float frow[4][FFD];
    int d   = threadIdx.x;
    int bs0 = blockIdx.x * 4;
#pragma unroll
    for (int e = d; e < 4 * FFD; e += 64) ((float*)frow)[e] = ff[bs0 * FFD + e];
    __syncthreads();
    const float* w = W + l * FFD * DD;
    float bv = bias[l * DD + d];
    float acc[4] = {bv, bv, bv, bv};
#pragma unroll 4
    for (int i = 0; i < FFD; ++i) {
        float wv = w[i * DD + d];
        acc[0] += frow[0][i]*wv; acc[1] += frow[1][i]*wv;
        acc[2] += frow[2][i]*wv; acc[3] += frow[3][i]*wv;
    }
    float gg = g[l * DD + d], bb = bp[l * DD + d];
#pragma unroll
    for (int r = 0; r < 4; ++r) {
        int bs = bs0 + r;
        float a = acc[r] + h[bs * DD + d];
        float sum = a;
        for (int off = 32; off; off >>= 1) sum += __shfl_xor(sum, off);
        float mean = sum * (1.f / 64.f);
        float dx = a - mean;
        float vs = dx * dx;
        for (int off = 32; off; off >>= 1) vs += __shfl_xor(vs, off);
        float rstd = rsqrtf(vs * (1.f / 64.f) + 1e-5f);
        h[bs * DD + d] = dx * rstd * gg + bb;
    }
}

// ---------------- mean pool over sequence (8-way split) ----------------
__global__ __launch_bounds__(64) void k_pool(const float* __restrict__ h, float* __restrict__ pp) {
    int b = blockIdx.x, c = blockIdx.y, d = threadIdx.x;
    const float* hp = h + (b * SS + c * 128) * DD + d;
    float acc = 0.f;
#pragma unroll 8
    for (int s = 0; s < 128; ++s) acc += hp[s * DD];
    pp[(b * 8 + c) * DD + d] = acc;
}

// ---------------- MLP head -> angles ----------------
__global__ __launch_bounds__(64) void k_head(const float* __restrict__ pp,
                                             const float* __restrict__ Wp1, const float* __restrict__ bp1,
                                             const float* __restrict__ Wp2, const float* __restrict__ bp2,
                                             float* __restrict__ angles) {
    __shared__ float pool_s[DD];
    __shared__ float hid[32];
    int b = blockIdx.x; int t = threadIdx.x;
    float acc = 0.f;
#pragma unroll
    for (int c = 0; c < 8; ++c) acc += pp[(b * 8 + c) * DD + t];
    pool_s[t] = acc * (1.f / 1024.f);
    __syncthreads();
    if (t < 32) {
        float a = bp1[t];
        for (int i = 0; i < DD; ++i) a += pool_s[i] * Wp1[i * 32 + t];
        hid[t] = fmaxf(a, 0.f);
    }
    __syncthreads();
    if (t < NQ) {
        float a = bp2[t];
        for (int j = 0; j < 32; ++j) a += hid[j] * Wp2[j * NQ + t];
        angles[b * NQ + t] = tanhf(a) * 3.14159265358979f;
    }
}

// ---------------- quantum circuit + Z-exps; writes psi for eigensolver ------
__global__ __launch_bounds__(64) void k_qcirc(const float* __restrict__ angles,
                                              const float* __restrict__ qw,
                                              float* __restrict__ out,
                                              float2* __restrict__ psig) {
    int b = blockIdx.x; int L = threadIdx.x;
    float ar[4], ai[4];
#pragma unroll
    for (int r = 0; r < 4; ++r) { ar[r] = 0.f; ai[r] = 0.f; }
    if (L == 0) ar[0] = 1.f;

    const float* ang = angles + b * NQ;
    for (int l = 0; l < QLAY; ++l) {
#pragma unroll
        for (int w = 0; w < NQ; ++w) {
            int p = 7 - w;
            float half = 0.5f * ang[w];
            float c = cosf(half), s = sinf(half);
            if (p == 7) {
#pragma unroll
                for (int lo = 0; lo < 2; ++lo) {
                    int hi = lo + 2;
                    float r0=ar[lo], m0=ai[lo], r1=ar[hi], m1=ai[hi];
                    ar[lo] = c*r0 + s*m1;  ai[lo] = c*m0 - s*r1;
                    ar[hi] = c*r1 + s*m0;  ai[hi] = c*m1 - s*r0;
                }
            } else if (p == 6) {
#pragma unroll
                for (int base = 0; base < 4; base += 2) {
                    int lo = base, hi = base + 1;
                    float r0=ar[lo], m0=ai[lo], r1=ar[hi], m1=ai[hi];
                    ar[lo] = c*r0 + s*m1;  ai[lo] = c*m0 - s*r1;
                    ar[hi] = c*r1 + s*m0;  ai[hi] = c*m1 - s*r0;
                }
            } else {
                int mask = 1 << p;
#pragma unroll
                for (int r = 0; r < 4; ++r) {
                    float pre = __shfl_xor(ar[r], mask);
                    float pim = __shfl_xor(ai[r], mask);
                    float nr = c*ar[r] + s*pim;
                    float ni = c*ai[r] - s*pre;
                    ar[r] = nr; ai[r] = ni;
                }
            }
        }
#pragma unroll
        for (int w = 0; w < NQ; ++w) {
            const float* p3 = qw + (l * NQ + w) * 3;
            float phi = p3[0], th = p3[1], om = p3[2];
            float ct = cosf(0.5f * th), st = sinf(0.5f * th);
            float al = 0.5f * (phi + om), be = 0.5f * (phi - om);
            float ca = cosf(al), sa = sinf(al), cb = cosf(be), sb = sinf(be);
            float u00r =  ct * ca, u00i = -ct * sa;
            float u01r = -st * cb, u01i = -st * sb;
            float u10r =  st * cb, u10i = -st * sb;
            float u11r =  ct * ca, u11i =  ct * sa;
            int p = 7 - w;
            if (p >= 6) {
#pragma unroll
                for (int pi_ = 0; pi_ < 2; ++pi_) {
                    int lo = (p == 7) ? pi_ : pi_ * 2;
                    int hi = (p == 7) ? pi_ + 2 : pi_ * 2 + 1;
                    float r0=ar[lo], m0=ai[lo], r1=ar[hi], m1=ai[hi];
                    ar[lo] = u00r*r0 - u00i*m0 + u01r*r1 - u01i*m1;
                    ai[lo] = u00r*m0 + u00i*r0 + u01r*m1 + u01i*r1;
                    ar[hi] = u10r*r0 - u10i*m0 + u11r*r1 - u11i*m1;
                    ai[hi] = u10r*m0 + u10i*r0 + u11r*m1 + u11i*r1;
                }
            } else {
                int mask = 1 << p;
                int bit = (L >> p) & 1;
                float car = bit ? u11r : u00r, cai = bit ? u11i : u00i;
                float cpr = bit ? u10r : u01r, cpi = bit ? u10i : u01i;
#pragma unroll
                for (int r = 0; r < 4; ++r) {
                    float pre = __shfl_xor(ar[r], mask);
                    float pim = __shfl_xor(ai[r], mask);
                    float nr = car*ar[r] - cai*ai[r] + cpr*pre - cpi*pim;
                    float ni = car*ai[r] + cai*ar[r] + cpr*pim + cpi*pre;
                    ar[r] = nr; ai[r] = ni;
                }
            }
        }
        { float t0=ar[2]; ar[2]=ar[3]; ar[3]=t0; t0=ai[2]; ai[2]=ai[3]; ai[3]=t0; }
        ar[1]=__shfl_xor(ar[1],32); ai[1]=__shfl_xor(ai[1],32);
        ar[3]=__shfl_xor(ar[3],32); ai[3]=__shfl_xor(ai[3],32);
#pragma unroll
        for (int w = 2; w <= 6; ++w) {
            int pc = 7 - w, pt = 6 - w;
            int tm = 1 << pt;
            bool ctrl = (L >> pc) & 1;
#pragma unroll
            for (int r = 0; r < 4; ++r) {
                float swr = __shfl_xor(ar[r], tm);
                float swi = __shfl_xor(ai[r], tm);
                ar[r] = ctrl ? swr : ar[r];
                ai[r] = ctrl ? swi : ai[r];
            }
        }
        {
            bool ctrl = L & 1;
            float n0r = ctrl ? ar[2] : ar[0], n2r = ctrl ? ar[0] : ar[2];
            float n0i = ctrl ? ai[2] : ai[0], n2i = ctrl ? ai[0] : ai[2];
            float n1r = ctrl ? ar[3] : ar[1], n3r = ctrl ? ar[1] : ar[3];
            float n1i = ctrl ? ai[3] : ai[1], n3i = ctrl ? ai[1] : ai[3];
            ar[0]=n0r; ar[1]=n1r; ar[2]=n2r; ar[3]=n3r;
            ai[0]=n0i; ai[1]=n1i; ai[2]=n2i; ai[3]=n3i;
        }
    }

    {
        float p0 = ar[0]*ar[0]+ai[0]*ai[0];
        float p1 = ar[1]*ar[1]+ai[1]*ai[1];
        float p2 = ar[2]*ar[2]+ai[2]*ai[2];
        float p3 = ar[3]*ar[3]+ai[3]*ai[3];
        float z0 = p0 + p1 - p2 - p3;
        float z1 = p0 - p1 + p2 - p3;
        float zs = p0 + p1 + p2 + p3;
        float z2 = (L & 32) ? -zs : zs;
#pragma unroll
        for (int off = 1; off < 64; off <<= 1) {
            z0 += __shfl_xor(z0, off);
            z1 += __shfl_xor(z1, off);
            z2 += __shfl_xor(z2, off);
        }
        if (L == 0) {
            out[b * NC + 0] = z0;
            out[b * NC + 1] = z1;
            out[b * NC + 2] = z2;
        }
    }

#pragma unroll
    for (int r = 0; r < 4; ++r) psig[(b << 8) | (r << 6) | L] = make_float2(ar[r], ai[r]);
}

// ---------------- eigensolver: one-sided Jacobi, column-per-lane, LDS mirror
// 4 blocks x 1 wave; lane = (batch-in-block<<4)|column. (64,1) launch bounds
// unlock the full VGPR budget so the column + partner stay register-resident.
__global__ __launch_bounds__(64, 1) void k_qeig(const float2* __restrict__ psig,
                                                float* __restrict__ out) {
    __shared__ float4 Ps[64 * 9];     // 64 columns, stride 9 float4 (8 used + 1 pad)
    int g = blockIdx.x;               // 0..3
    int L = threadIdx.x;
    int bl = L >> 4;                  // batch within block
    int c  = L & 15;                  // my column
    const float2* src = psig + ((g * 4 + bl) << 8);
    float gr[16], gi[16];
#pragma unroll
    for (int k = 0; k < 16; ++k) {
        float2 t = src[k * 16 + c];
        gr[k] = t.x; gi[k] = t.y;
    }
    float4* myP = Ps + L * 9;
#pragma unroll
    for (int k = 0; k < 8; ++k)
        myP[k] = make_float4(gr[2*k], gi[2*k], gr[2*k+1], gi[2*k+1]);
    // single wave: DS ops execute in program order; no barrier needed

    for (int sweep = 0; sweep < NSWEEP; ++sweep) {
        for (int rd = 0; rd < 15; ++rd) {
            int q;
            if (c == 15) q = rd;
            else {
                int u = c - rd; if (u < 0) u += 15;
                if (u == 0) q = 15;
                else { q = rd + 15 - u; if (q >= 15) q -= 15; }
            }
            int plane = (L & 48) | q;
            const float4* pp4 = Ps + plane * 9;
            float4 pc[8];
#pragma unroll
            for (int k = 0; k < 8; ++k) pc[k] = pp4[k];
            float alm = 0.f, d = 0.f, e = 0.f;
#pragma unroll
            for (int k = 0; k < 8; ++k) {
                float g0r = gr[2*k], g0i = gi[2*k], g1r = gr[2*k+1], g1i = gi[2*k+1];
                alm += g0r*g0r + g0i*g0i + g1r*g1r + g1i*g1i;
                d   += g0r*pc[k].x + g0i*pc[k].y + g1r*pc[k].z + g1i*pc[k].w;
                e   += g0r*pc[k].y - g0i*pc[k].x + g1r*pc[k].w - g1i*pc[k].z;
            }
            float bep = __shfl(alm, plane);           // |partner|^2
            float g2 = d*d + e*e;
            float cth = 1.f, sth = 0.f, cph = 1.f, sph = 0.f;
            if (g2 > 1e-26f) {
                float gn = sqrtf(g2);
                float ginv = 1.f / gn;
                cph = d * ginv; sph = -e * ginv;       // conj(gamma)/|gamma|
                float tau = (alm - bep) * (0.5f * ginv);
                float t = ((tau >= 0.f) ? 1.f : -1.f) / (fabsf(tau) + sqrtf(1.f + tau*tau));
                cth = rsqrtf(1.f + t*t);
                sth = t * cth;
            }
#pragma unroll
            for (int k = 0; k < 8; ++k) {
                float er0 = cph*pc[k].x - sph*pc[k].y;
                float ei0 = cph*pc[k].y + sph*pc[k].x;
                float er1 = cph*pc[k].z - sph*pc[k].w;
                float ei1 = cph*pc[k].w + sph*pc[k].z;
                gr[2*k]   = cth * gr[2*k]   + sth * er0;
                gi[2*k]   = cth * gi[2*k]   + sth * ei0;
                gr[2*k+1] = cth * gr[2*k+1] + sth * er1;
                gi[2*k+1] = cth * gi[2*k+1] + sth * ei1;
            }
#pragma unroll
            for (int k = 0; k < 8; ++k)
                myP[k] = make_float4(gr[2*k], gi[2*k], gr[2*k+1], gi[2*k+1]);
        }
    }

    float lam = 0.f;
#pragma unroll
    for (int k = 0; k < 16; ++k) lam += gr[k]*gr[k] + gi[k]*gi[k];
    float ev = fminf(fmaxf(lam, 1e-10f), 1.0f);
    float term = -ev * logf(ev);
#pragma unroll
    for (int off = 1; off <= 8; off <<= 1) term += __shfl_xor(term, off);
    if (c == 0) out[BB * NC + g * 4 + bl] = term;
}

extern "C" void kernel_launch(void* const* d_in, const int* in_sizes, int n_in,
                              void* d_out, int out_size, void* d_ws, size_t ws_size,
                              hipStream_t stream) {
    const float* x    = (const float*)d_in[0];
    const float* Wemb = (const float*)d_in[1];
    const float* bemb = (const float*)d_in[2];
    const float* Wq   = (const float*)d_in[3];
    const float* bq   = (const float*)d_in[4];
    const float* Wk   = (const float*)d_in[5];
    const float* bk   = (const float*)d_in[6];
    const float* Wv   = (const float*)d_in[7];
    const float* bv   = (const float*)d_in[8];
    const float* Wo   = (const float*)d_in[9];
    const float* bo   = (const float*)d_in[10];
    const float* ln1g = (const float*)d_in[11];
    const float* ln1b = (const float*)d_in[12];
    const float* ln2g = (const float*)d_in[13];
    const float* ln2b = (const float*)d_in[14];
    const float* Wf1  = (const float*)d_in[15];
    const float* bf1  = (const float*)d_in[16];
    const float* Wf2  = (const float*)d_in[17];
    const float* bf2  = (const float*)d_in[18];
    const float* Wp1  = (const float*)d_in[19];
    const float* bp1  = (const float*)d_in[20];
    const float* Wp2  = (const float*)d_in[21];
    const float* bp2  = (const float*)d_in[22];
    const float* qwts = (const float*)d_in[23];
    float* out = (float*)d_out;

    const size_t M = 1u << 20;           // 1M floats = B*S*D
    auto needF = [&](int nch) {
        return (size_t)(4.5 * M) + (size_t)nch * M + (size_t)nch * BHS_TOT + BB * 8 * DD + 16384;
    };
    int nch = (ws_size >= needF(4) * sizeof(float)) ? 4 : 2;

    float* ws     = (float*)d_ws;
    float* h      = ws;                               // 1M
    hf2*   qh     = (hf2*)(ws + M);                   // 0.5M floats
    hf2*   kvh    = (hf2*)(ws + M + M / 2);           // 1M floats
    float* ff     = ws + (M * 5) / 2;                 // 2M
    float* Apart  = ws + (M * 9) / 2;                 // nch*M
    float* lpart  = Apart + (size_t)nch * M;          // nch*BHS_TOT
    float* pp     = lpart + (size_t)nch * BHS_TOT;    // [16][8][64]
    float* angls  = pp + BB * 8 * DD;                 // [B,NQ]
    float2* psig  = (float2*)(angls + 256);           // [16][256] float2

    k_embed<<<BB * SS, 64, 0, stream>>>(x, Wemb, bemb, h);
    for (int l = 0; l < NLAYER; ++l) {
        k_qkv<<<BB * SS / 4, 64, 0, stream>>>(h, Wq, bq, Wk, bk, Wv, bv, qh, kvh, l);
        k_attn<<<dim3(BB * HH, 4 * nch), 256, 0, stream>>>(qh, (const float4*)kvh, Apart, lpart, nch);
        k_projln<<<BB * SS / 4, 64, 0, stream>>>(Apart, lpart, Wo, bo, ln1g, ln1b, h, l, nch);
        k_ffn1<<<BB * SS / 4, 128, 0, stream>>>(h, Wf1, bf1, ff, l);
        k_ffn2ln<<<BB * SS / 4, 64, 0, stream>>>(ff, Wf2, bf2, ln2g, ln2b, h, l);
    }
    k_pool<<<dim3(BB, 8), 64, 0, stream>>>(h, pp);
    k_head<<<BB, 64, 0, stream>>>(pp, Wp1, bp1, Wp2, bp2, angls);
    k_qcirc<<<BB, 64, 0, stream>>>(angls, qwts, out, psig);
    k_qeig<<<4, 64, 0, stream>>>(psig, out);
}

// Round 13
// 428.631 us; speedup vs baseline: 1.1294x; 1.0694x over previous
//
#include <hip/hip_runtime.h>
#include <math.h>

#define BB 16
#define SS 1024
#define NF 5
#define DD 64
#define HH 8
#define HDIM 8
#define NLAYER 2
#define FFD 128
#define NQ 8
#define QLAY 3
#define NC 3
#define NSWEEP 8
#define BHS_TOT (BB * HH * SS)   // 131072 = 1<<17

typedef __fp16 hf2 __attribute__((ext_vector_type(2)));
__device__ inline hf2 ash2(float f) { union { float f; hf2 h; } u; u.f = f; return u.h; }

// ---------------- embed + positional encoding ----------------
__global__ __launch_bounds__(64) void k_embed(const float* __restrict__ x,
                                              const float* __restrict__ Wemb,
                                              const float* __restrict__ bemb,
                                              float* __restrict__ h) {
    int bs = blockIdx.x;            // 0..B*S-1
    int s  = bs & (SS - 1);
    int d  = threadIdx.x;           // 0..63
    const float* xr = x + bs * NF;
    float acc = bemb[d];
#pragma unroll
    for (int f = 0; f < NF; ++f) acc += xr[f] * Wemb[f * DD + d];
    int i = d >> 1;
    float div = expf((float)(2 * i) * (-9.210340371976184f / 64.0f));
    float ang = (float)s * div;
    float pe = (d & 1) ? cosf(ang) : sinf(ang);
    h[bs * DD + d] = acc + pe;
}

// ---------------- fused q,k,v projection (4 rows/block; f16 packed out) -----
__global__ __launch_bounds__(64) void k_qkv(const float* __restrict__ h,
                                            const float* __restrict__ Wq, const float* __restrict__ bq,
                                            const float* __restrict__ Wk, const float* __restrict__ bk,
                                            const float* __restrict__ Wv, const float* __restrict__ bv,
                                            hf2* __restrict__ qh, hf2* __restrict__ kvh, int l) {
    __shared__ float hrow[4][DD];
    int d   = threadIdx.x;
    int bs0 = blockIdx.x * 4;
#pragma unroll
    for (int r = 0; r < 4; ++r) hrow[r][d] = h[(bs0 + r) * DD + d];
    __syncthreads();
    const float* wq = Wq + l * DD * DD;
    const float* wk = Wk + l * DD * DD;
    const float* wv = Wv + l * DD * DD;
    float aq[4], ak[4], av[4];
    float bqv = bq[l * DD + d], bkv = bk[l * DD + d], bvv = bv[l * DD + d];
#pragma unroll
    for (int r = 0; r < 4; ++r) { aq[r] = bqv; ak[r] = bkv; av[r] = bvv; }
#pragma unroll 4
    for (int i = 0; i < DD; ++i) {
        float wqv = wq[i * DD + d], wkv = wk[i * DD + d], wvv = wv[i * DD + d];
#pragma unroll
        for (int r = 0; r < 4; ++r) {
            float hv = hrow[r][i];
            aq[r] += hv * wqv; ak[r] += hv * wkv; av[r] += hv * wvv;
        }
    }
    int hh = d >> 3, hd = d & 7;
    const float qs = 0.3535533906f;
    float aqp[4], akp[4];
#pragma unroll
    for (int r = 0; r < 4; ++r) { aqp[r] = __shfl_xor(aq[r], 1); akp[r] = __shfl_xor(ak[r], 1); }
    if ((hd & 1) == 0) {
#pragma unroll
        for (int r = 0; r < 4; ++r) {
            int bs = bs0 + r;
            int b = bs >> 10, s = bs & 1023;
            int bh = b * HH + hh;
            int bhs = (bh << 10) | s;
            qh[bhs * 4 + (hd >> 1)] = __builtin_amdgcn_cvt_pkrtz(aq[r] * qs, aqp[r] * qs);
            int tp = s >> 1, par = s & 1;
            kvh[(bh * 512 + tp) * 16 + par * 4 + (hd >> 1)] =
                __builtin_amdgcn_cvt_pkrtz(ak[r], akp[r]);
        }
    }
#pragma unroll
    for (int r = 0; r < 4; r += 2) {
        int bs = bs0 + r;
        int b = bs >> 10, s = bs & 1023;
        int bh = b * HH + hh;
        int tp = s >> 1;
        kvh[(bh * 512 + tp) * 16 + 8 + hd] = __builtin_amdgcn_cvt_pkrtz(av[r], av[r + 1]);
    }
}

// ---------------- attention: f16 dot2 math, 1 row/thread, t chunked ---------
__global__ __launch_bounds__(256) void k_attn(const hf2* __restrict__ qh,
                                              const float4* __restrict__ kvh4,
                                              float* __restrict__ Apart,   // [nch][BHS][8]
                                              float* __restrict__ lpart,   // [nch][BHS]
                                              int nch) {
    int bh  = blockIdx.x;             // 0..127
    int sg  = blockIdx.y & 3;
    int ch  = blockIdx.y >> 2;
    int tid = threadIdx.x;
    int s   = sg * 256 + tid;
    int tpc = 512 / nch;              // t-pairs per chunk
    const float4* kp = kvh4 + (size_t)(bh * 512 + ch * tpc) * 4;
    float4 qv = ((const float4*)qh)[(bh << 10) | s];
    hf2 q01 = ash2(qv.x), q23 = ash2(qv.y), q45 = ash2(qv.z), q67 = ash2(qv.w);
    hf2 one2 = __builtin_amdgcn_cvt_pkrtz(1.f, 1.f);
    float ls = 0.f;
    float A[8] = {0,0,0,0,0,0,0,0};
#pragma unroll 2
    for (int t = 0; t < tpc; ++t) {
        float4 f0 = kp[4*t], f1 = kp[4*t+1], f2 = kp[4*t+2], f3 = kp[4*t+3];
        float sc0 = __builtin_amdgcn_fdot2(q67, ash2(f0.w),
                    __builtin_amdgcn_fdot2(q45, ash2(f0.z),
                    __builtin_amdgcn_fdot2(q23, ash2(f0.y),
                    __builtin_amdgcn_fdot2(q01, ash2(f0.x), 0.f, false), false), false), false);
        float sc1 = __builtin_amdgcn_fdot2(q67, ash2(f1.w),
                    __builtin_amdgcn_fdot2(q45, ash2(f1.z),
                    __builtin_amdgcn_fdot2(q23, ash2(f1.y),
                    __builtin_amdgcn_fdot2(q01, ash2(f1.x), 0.f, false), false), false), false);
        float p0 = __expf(sc0), p1 = __expf(sc1);
        hf2 pp = __builtin_amdgcn_cvt_pkrtz(p0, p1);
        ls   = __builtin_amdgcn_fdot2(pp, one2,       ls,   false);
        A[0] = __builtin_amdgcn_fdot2(pp, ash2(f2.x), A[0], false);
        A[1] = __builtin_amdgcn_fdot2(pp, ash2(f2.y), A[1], false);
        A[2] = __builtin_amdgcn_fdot2(pp, ash2(f2.z), A[2], false);
        A[3] = __builtin_amdgcn_fdot2(pp, ash2(f2.w), A[3], false);
        A[4] = __builtin_amdgcn_fdot2(pp, ash2(f3.x), A[4], false);
        A[5] = __builtin_amdgcn_fdot2(pp, ash2(f3.y), A[5], false);
        A[6] = __builtin_amdgcn_fdot2(pp, ash2(f3.z), A[6], false);
        A[7] = __builtin_amdgcn_fdot2(pp, ash2(f3.w), A[7], false);
    }
    int bhs = (bh << 10) | s;
    float* arow = Apart + (((size_t)ch << 17) + bhs) * 8;
    ((float4*)arow)[0] = make_float4(A[0], A[1], A[2], A[3]);
    ((float4*)arow)[1] = make_float4(A[4], A[5], A[6], A[7]);
    lpart[((size_t)ch << 17) + bhs] = ls;
}

// ---------------- attention combine + O projection + residual + layernorm ----
__global__ __launch_bounds__(64) void k_projln(const float* __restrict__ Apart,
                                               const float* __restrict__ lpart,
                                               const float* __restrict__ Wo, const float* __restrict__ bo,
                                               const float* __restrict__ g, const float* __restrict__ bp,
                                               float* __restrict__ h, int l, int nch) {
    __shared__ float orow[4][DD];
    int d   = threadIdx.x;
    int bs0 = blockIdx.x * 4;
    int hh = d >> 3, hd = d & 7;
#pragma unroll
    for (int r = 0; r < 4; ++r) {
        int bs = bs0 + r;
        int b = bs >> 10, s = bs & 1023;
        int bhs = ((b * HH + hh) << 10) | s;
        float a = 0.f, lt = 0.f;
        for (int ch = 0; ch < nch; ++ch) {
            a  += Apart[(((size_t)ch << 17) + bhs) * 8 + hd];
            lt += lpart[((size_t)ch << 17) + bhs];
        }
        orow[r][d] = a / lt;
    }
    __syncthreads();
    const float* w = Wo + l * DD * DD;
    float bias = bo[l * DD + d];
    float acc[4] = {bias, bias, bias, bias};
#pragma unroll 4
    for (int i = 0; i < DD; ++i) {
        float wv = w[i * DD + d];
        acc[0] += orow[0][i]*wv; acc[1] += orow[1][i]*wv;
        acc[2] += orow[2][i]*wv; acc[3] += orow[3][i]*wv;
    }
    float gg = g[l * DD + d], bb = bp[l * DD + d];
#pragma unroll
    for (int r = 0; r < 4; ++r) {
        int bs = bs0 + r;
        float a = acc[r] + h[bs * DD + d];
        float sum = a;
        for (int off = 32; off; off >>= 1) sum += __shfl_xor(sum, off);
        float mean = sum * (1.f / 64.f);
        float dx = a - mean;
        float vs = dx * dx;
        for (int off = 32; off; off >>= 1) vs += __shfl_xor(vs, off);
        float rstd = rsqrtf(vs * (1.f / 64.f) + 1e-5f);
        h[bs * DD + d] = dx * rstd * gg + bb;
    }
}

// ---------------- FFN layer 1 (relu), 4 rows/block ----------------
__global__ __launch_bounds__(128) void k_ffn1(const float* __restrict__ h,
                                              const float* __restrict__ W, const float* __restrict__ bias,
                                              float* __restrict__ ff, int l) {
    __shared__ float hrow[4][DD];
    int f   = threadIdx.x;
    int bs0 = blockIdx.x * 4;
#pragma unroll
    for (int e = f; e < 4 * DD; e += 128) ((float*)hrow)[e] = h[bs0 * DD + e];
    __syncthreads();
    const float* w = W + l * DD * FFD;
    float bv = bias[l * FFD + f];
    float acc[4] = {bv, bv, bv, bv};
#pragma unroll 4
    for (int i = 0; i < DD; ++i) {
        float wv = w[i * FFD + f];
        acc[0] += hrow[0][i]*wv; acc[1] += hrow[1][i]*wv;
        acc[2] += hrow[2][i]*wv; acc[3] += hrow[3][i]*wv;
    }
#pragma unroll
    for (int r = 0; r < 4; ++r) ff[(bs0 + r) * FFD + f] = fmaxf(acc[r], 0.f);
}

// ---------------- FFN layer 2 + residual + layernorm, 4 rows/block ----------
__global__ __launch_bounds__(64) void k_ffn2ln(const float* __restrict__ ff,
                                               const float* __restrict__ W, const float* __restrict__ bias,
                                               const float* __restrict__ g, const float* __restrict__ bp,
                                               float* __restrict__ h, int l) {
    __shared__ float frow[4][FFD];
    int d   = threadIdx.x;
    int bs0 = blockIdx.x * 4;
#pragma unroll
    for (int e = d; e < 4 * FFD; e += 64) ((float*)frow)[e] = ff[bs0 * FFD + e];
    __syncthreads();
    const float* w = W + l * FFD * DD;
    float bv = bias[l * DD + d];
    float acc[4] = {bv, bv, bv, bv};
#pragma unroll 4
    for (int i = 0; i < FFD; ++i) {
        float wv = w[i * DD + d];
        acc[0] += frow[0][i]*wv; acc[1] += frow[1][i]*wv;
        acc[2] += frow[2][i]*wv; acc[3] += frow[3][i]*wv;
    }
    float gg = g[l * DD + d], bb = bp[l * DD + d];
#pragma unroll
    for (int r = 0; r < 4; ++r) {
        int bs = bs0 + r;
        float a = acc[r] + h[bs * DD + d];
        float sum = a;
        for (int off = 32; off; off >>= 1) sum += __shfl_xor(sum, off);
        float mean = sum * (1.f / 64.f);
        float dx = a - mean;
        float vs = dx * dx;
        for (int off = 32; off; off >>= 1) vs += __shfl_xor(vs, off);
        float rstd = rsqrtf(vs * (1.f / 64.f) + 1e-5f);
        h[bs * DD + d] = dx * rstd * gg + bb;
    }
}

// ---------------- mean pool over sequence (8-way split) ----------------
__global__ __launch_bounds__(64) void k_pool(const float* __restrict__ h, float* __restrict__ pp) {
    int b = blockIdx.x, c = blockIdx.y, d = threadIdx.x;
    const float* hp = h + (b * SS + c * 128) * DD + d;
    float acc = 0.f;
#pragma unroll 8
    for (int s = 0; s < 128; ++s) acc += hp[s * DD];
    pp[(b * 8 + c) * DD + d] = acc;
}

// ---------------- MLP head -> angles ----------------
__global__ __launch_bounds__(64) void k_head(const float* __restrict__ pp,
                                             const float* __restrict__ Wp1, const float* __restrict__ bp1,
                                             const float* __restrict__ Wp2, const float* __restrict__ bp2,
                                             float* __restrict__ angles) {
    __shared__ float pool_s[DD];
    __shared__ float hid[32];
    int b = blockIdx.x; int t = threadIdx.x;
    float acc = 0.f;
#pragma unroll
    for (int c = 0; c < 8; ++c) acc += pp[(b * 8 + c) * DD + t];
    pool_s[t] = acc * (1.f / 1024.f);
    __syncthreads();
    if (t < 32) {
        float a = bp1[t];
        for (int i = 0; i < DD; ++i) a += pool_s[i] * Wp1[i * 32 + t];
        hid[t] = fmaxf(a, 0.f);
    }
    __syncthreads();
    if (t < NQ) {
        float a = bp2[t];
        for (int j = 0; j < 32; ++j) a += hid[j] * Wp2[j * NQ + t];
        angles[b * NQ + t] = tanhf(a) * 3.14159265358979f;
    }
}

// ---------------- quantum circuit + Z-exps; writes psi for eigensolver ------
__global__ __launch_bounds__(64) void k_qcirc(const float* __restrict__ angles,
                                              const float* __restrict__ qw,
                                              float* __restrict__ out,
                                              float2* __restrict__ psig) {
    int b = blockIdx.x; int L = threadIdx.x;
    float ar[4], ai[4];
#pragma unroll
    for (int r = 0; r < 4; ++r) { ar[r] = 0.f; ai[r] = 0.f; }
    if (L == 0) ar[0] = 1.f;

    const float* ang = angles + b * NQ;
    for (int l = 0; l < QLAY; ++l) {
#pragma unroll
        for (int w = 0; w < NQ; ++w) {
            int p = 7 - w;
            float half = 0.5f * ang[w];
            float c = cosf(half), s = sinf(half);
            if (p == 7) {
#pragma unroll
                for (int lo = 0; lo < 2; ++lo) {
                    int hi = lo + 2;
                    float r0=ar[lo], m0=ai[lo], r1=ar[hi], m1=ai[hi];
                    ar[lo] = c*r0 + s*m1;  ai[lo] = c*m0 - s*r1;
                    ar[hi] = c*r1 + s*m0;  ai[hi] = c*m1 - s*r0;
                }
            } else if (p == 6) {
#pragma unroll
                for (int base = 0; base < 4; base += 2) {
                    int lo = base, hi = base + 1;
                    float r0=ar[lo], m0=ai[lo], r1=ar[hi], m1=ai[hi];
                    ar[lo] = c*r0 + s*m1;  ai[lo] = c*m0 - s*r1;
                    ar[hi] = c*r1 + s*m0;  ai[hi] = c*m1 - s*r0;
                }
            } else {
                int mask = 1 << p;
#pragma unroll
                for (int r = 0; r < 4; ++r) {
                    float pre = __shfl_xor(ar[r], mask);
                    float pim = __shfl_xor(ai[r], mask);
                    float nr = c*ar[r] + s*pim;
                    float ni = c*ai[r] - s*pre;
                    ar[r] = nr; ai[r] = ni;
                }
            }
        }
#pragma unroll
        for (int w = 0; w < NQ; ++w) {
            const float* p3 = qw + (l * NQ + w) * 3;
            float phi = p3[0], th = p3[1], om = p3[2];
            float ct = cosf(0.5f * th), st = sinf(0.5f * th);
            float al = 0.5f * (phi + om), be = 0.5f * (phi - om);
            float ca = cosf(al), sa = sinf(al), cb = cosf(be), sb = sinf(be);
            float u00r =  ct * ca, u00i = -ct * sa;
            float u01r = -st * cb, u01i = -st * sb;
            float u10r =  st * cb, u10i = -st * sb;
            float u11r =  ct * ca, u11i =  ct * sa;
            int p = 7 - w;
            if (p >= 6) {
#pragma unroll
                for (int pi_ = 0; pi_ < 2; ++pi_) {
                    int lo = (p == 7) ? pi_ : pi_ * 2;
                    int hi = (p == 7) ? pi_ + 2 : pi_ * 2 + 1;
                    float r0=ar[lo], m0=ai[lo], r1=ar[hi], m1=ai[hi];
                    ar[lo] = u00r*r0 - u00i*m0 + u01r*r1 - u01i*m1;
                    ai[lo] = u00r*m0 + u00i*r0 + u01r*m1 + u01i*r1;
                    ar[hi] = u10r*r0 - u10i*m0 + u11r*r1 - u11i*m1;
                    ai[hi] = u10r*m0 + u10i*r0 + u11r*m1 + u11i*r1;
                }
            } else {
                int mask = 1 << p;
                int bit = (L >> p) & 1;
                float car = bit ? u11r : u00r, cai = bit ? u11i : u00i;
                float cpr = bit ? u10r : u01r, cpi = bit ? u10i : u01i;
#pragma unroll
                for (int r = 0; r < 4; ++r) {
                    float pre = __shfl_xor(ar[r], mask);
                    float pim = __shfl_xor(ai[r], mask);
                    float nr = car*ar[r] - cai*ai[r] + cpr*pre - cpi*pim;
                    float ni = car*ai[r] + cai*ar[r] + cpr*pim + cpi*pre;
                    ar[r] = nr; ai[r] = ni;
                }
            }
        }
        { float t0=ar[2]; ar[2]=ar[3]; ar[3]=t0; t0=ai[2]; ai[2]=ai[3]; ai[3]=t0; }
        ar[1]=__shfl_xor(ar[1],32); ai[1]=__shfl_xor(ai[1],32);
        ar[3]=__shfl_xor(ar[3],32); ai[3]=__shfl_xor(ai[3],32);
#pragma unroll
        for (int w = 2; w <= 6; ++w) {
            int pc = 7 - w, pt = 6 - w;
            int tm = 1 << pt;
            bool ctrl = (L >> pc) & 1;
#pragma unroll
            for (int r = 0; r < 4; ++r) {
                float swr = __shfl_xor(ar[r], tm);
                float swi = __shfl_xor(ai[r], tm);
                ar[r] = ctrl ? swr : ar[r];
                ai[r] = ctrl ? swi : ai[r];
            }
        }
        {
            bool ctrl = L & 1;
            float n0r = ctrl ? ar[2] : ar[0], n2r = ctrl ? ar[0] : ar[2];
            float n0i = ctrl ? ai[2] : ai[0], n2i = ctrl ? ai[0] : ai[2];
            float n1r = ctrl ? ar[3] : ar[1], n3r = ctrl ? ar[1] : ar[3];
            float n1i = ctrl ? ai[3] : ai[1], n3i = ctrl ? ai[1] : ai[3];
            ar[0]=n0r; ar[1]=n1r; ar[2]=n2r; ar[3]=n3r;
            ai[0]=n0i; ai[1]=n1i; ai[2]=n2i; ai[3]=n3i;
        }
    }

    {
        float p0 = ar[0]*ar[0]+ai[0]*ai[0];
        float p1 = ar[1]*ar[1]+ai[1]*ai[1];
        float p2 = ar[2]*ar[2]+ai[2]*ai[2];
        float p3 = ar[3]*ar[3]+ai[3]*ai[3];
        float z0 = p0 + p1 - p2 - p3;
        float z1 = p0 - p1 + p2 - p3;
        float zs = p0 + p1 + p2 + p3;
        float z2 = (L & 32) ? -zs : zs;
#pragma unroll
        for (int off = 1; off < 64; off <<= 1) {
            z0 += __shfl_xor(z0, off);
            z1 += __shfl_xor(z1, off);
            z2 += __shfl_xor(z2, off);
        }
        if (L == 0) {
            out[b * NC + 0] = z0;
            out[b * NC + 1] = z1;
            out[b * NC + 2] = z2;
        }
    }

#pragma unroll
    for (int r = 0; r < 4; ++r) psig[(b << 8) | (r << 6) | L] = make_float2(ar[r], ai[r]);
}

// ---------------- eigensolver: one-sided Jacobi, 4 lanes per column ---------
// 16 blocks (one batch each) x 1 wave. lane = (col<<2)|seg; each lane holds
// elements 4*seg..4*seg+3 of its column. Partner column via 8 shfls; dots via
// lane-local partials + 2-level quad xor-reduction. No LDS in the loop.
// Phase-folded select-free update (per-column phases don't affect rho=MM^H).
__global__ __launch_bounds__(64) void k_qeig(const float2* __restrict__ psig,
                                             float* __restrict__ out) {
    int b = blockIdx.x;               // 0..15
    int L = threadIdx.x;
    int c   = L >> 2;                 // my column
    int seg = L & 3;                  // my segment (4 elements)
    const float2* src = psig + (b << 8);
    float gr[4], gi[4];
#pragma unroll
    for (int j = 0; j < 4; ++j) {
        float2 t = src[(seg * 4 + j) * 16 + c];
        gr[j] = t.x; gi[j] = t.y;
    }

    for (int sweep = 0; sweep < NSWEEP; ++sweep) {
        for (int rd = 0; rd < 15; ++rd) {
            int q;
            if (c == 15) q = rd;
            else {
                int u = c - rd; if (u < 0) u += 15;
                if (u == 0) q = 15;
                else { q = rd + 15 - u; if (q >= 15) q -= 15; }
            }
            int pl = (q << 2) | seg;
            float pgr[4], pgi[4];
#pragma unroll
            for (int j = 0; j < 4; ++j) {
                pgr[j] = __shfl(gr[j], pl);
                pgi[j] = __shfl(gi[j], pl);
            }
            float alm = 0.f, d = 0.f, e = 0.f;
#pragma unroll
            for (int j = 0; j < 4; ++j) {
                alm += gr[j]*gr[j] + gi[j]*gi[j];
                d   += gr[j]*pgr[j] + gi[j]*pgi[j];   // Re(mine^H partner)
                e   += gr[j]*pgi[j] - gi[j]*pgr[j];   // Im(mine^H partner)
            }
            // quad reduction (segments of one column)
            alm += __shfl_xor(alm, 1); d += __shfl_xor(d, 1); e += __shfl_xor(e, 1);
            alm += __shfl_xor(alm, 2); d += __shfl_xor(d, 2); e += __shfl_xor(e, 2);
            float bep = __shfl(alm, pl);              // |partner|^2
            float g2 = d*d + e*e;
            float cth = 1.f, sth = 0.f, cph = 1.f, sph = 0.f;
            if (g2 > 1e-26f) {
                float gn = sqrtf(g2);
                float ginv = 1.f / gn;
                cph = d * ginv; sph = -e * ginv;       // conj(gamma)/|gamma|
                float tau = (alm - bep) * (0.5f * ginv);
                float t = ((tau >= 0.f) ? 1.f : -1.f) / (fabsf(tau) + sqrtf(1.f + tau*tau));
                cth = rsqrtf(1.f + t*t);
                sth = t * cth;
            }
#pragma unroll
            for (int j = 0; j < 4; ++j) {
                float er = cph*pgr[j] - sph*pgi[j];
                float ei = cph*pgi[j] + sph*pgr[j];
                gr[j] = cth * gr[j] + sth * er;
                gi[j] = cth * gi[j] + sth * ei;
            }
        }
    }

    float lam = 0.f;
#pragma unroll
    for (int j = 0; j < 4; ++j) lam += gr[j]*gr[j] + gi[j]*gi[j];
    lam += __shfl_xor(lam, 1);
    lam += __shfl_xor(lam, 2);                        // full column norm^2
    float ev = fminf(fmaxf(lam, 1e-10f), 1.0f);
    float term = -ev * logf(ev);
    // sum across the 16 columns (xor masks 4..32 mix quads, per-quad values equal)
#pragma unroll
    for (int off = 4; off < 64; off <<= 1) term += __shfl_xor(term, off);
    if (L == 0) out[BB * NC + b] = term;
}

extern "C" void kernel_launch(void* const* d_in, const int* in_sizes, int n_in,
                              void* d_out, int out_size, void* d_ws, size_t ws_size,
                              hipStream_t stream) {
    const float* x    = (const float*)d_in[0];
    const float* Wemb = (const float*)d_in[1];
    const float* bemb = (const float*)d_in[2];
    const float* Wq   = (const float*)d_in[3];
    const float* bq   = (const float*)d_in[4];
    const float* Wk   = (const float*)d_in[5];
    const float* bk   = (const float*)d_in[6];
    const float* Wv   = (const float*)d_in[7];
    const float* bv   = (const float*)d_in[8];
    const float* Wo   = (const float*)d_in[9];
    const float* bo   = (const float*)d_in[10];
    const float* ln1g = (const float*)d_in[11];
    const float* ln1b = (const float*)d_in[12];
    const float* ln2g = (const float*)d_in[13];
    const float* ln2b = (const float*)d_in[14];
    const float* Wf1  = (const float*)d_in[15];
    const float* bf1  = (const float*)d_in[16];
    const float* Wf2  = (const float*)d_in[17];
    const float* bf2  = (const float*)d_in[18];
    const float* Wp1  = (const float*)d_in[19];
    const float* bp1  = (const float*)d_in[20];
    const float* Wp2  = (const float*)d_in[21];
    const float* bp2  = (const float*)d_in[22];
    const float* qwts = (const float*)d_in[23];
    float* out = (float*)d_out;

    const size_t M = 1u << 20;           // 1M floats = B*S*D
    auto needF = [&](int nch) {
        return (size_t)(4.5 * M) + (size_t)nch * M + (size_t)nch * BHS_TOT + BB * 8 * DD + 16384;
    };
    int nch = (ws_size >= needF(4) * sizeof(float)) ? 4 : 2;

    float* ws     = (float*)d_ws;
    float* h      = ws;                               // 1M
    hf2*   qh     = (hf2*)(ws + M);                   // 0.5M floats
    hf2*   kvh    = (hf2*)(ws + M + M / 2);           // 1M floats
    float* ff     = ws + (M * 5) / 2;                 // 2M
    float* Apart  = ws + (M * 9) / 2;                 // nch*M
    float* lpart  = Apart + (size_t)nch * M;          // nch*BHS_TOT
    float* pp     = lpart + (size_t)nch * BHS_TOT;    // [16][8][64]
    float* angls  = pp + BB * 8 * DD;                 // [B,NQ]
    float2* psig  = (float2*)(angls + 256);           // [16][256] float2

    k_embed<<<BB * SS, 64, 0, stream>>>(x, Wemb, bemb, h);
    for (int l = 0; l < NLAYER; ++l) {
        k_qkv<<<BB * SS / 4, 64, 0, stream>>>(h, Wq, bq, Wk, bk, Wv, bv, qh, kvh, l);
        k_attn<<<dim3(BB * HH, 4 * nch), 256, 0, stream>>>(qh, (const float4*)kvh, Apart, lpart, nch);
        k_projln<<<BB * SS / 4, 64, 0, stream>>>(Apart, lpart, Wo, bo, ln1g, ln1b, h, l, nch);
        k_ffn1<<<BB * SS / 4, 128, 0, stream>>>(h, Wf1, bf1, ff, l);
        k_ffn2ln<<<BB * SS / 4, 64, 0, stream>>>(ff, Wf2, bf2, ln2g, ln2b, h, l);
    }
    k_pool<<<dim3(BB, 8), 64, 0, stream>>>(h, pp);
    k_head<<<BB, 64, 0, stream>>>(pp, Wp1, bp1, Wp2, bp2, angls);
    k_qcirc<<<BB, 64, 0, stream>>>(angls, qwts, out, psig);
    k_qeig<<<BB, 64, 0, stream>>>(psig, out);
}

// Round 14
// 393.774 us; speedup vs baseline: 1.2294x; 1.0885x over previous
//
#include <hip/hip_runtime.h>
#include <math.h>

#define BB 16
#define SS 1024
#define NF 5
#define DD 64
#define HH 8
#define HDIM 8
#define NLAYER 2
#define FFD 128
#define NQ 8
#define QLAY 3
#define NC 3
#define NSWEEP 8
#define BHS_TOT (BB * HH * SS)   // 131072 = 1<<17

typedef __fp16 hf2 __attribute__((ext_vector_type(2)));
__device__ inline hf2 ash2(float f) { union { float f; hf2 h; } u; u.f = f; return u.h; }

// ---------------- embed + positional encoding ----------------
__global__ __launch_bounds__(64) void k_embed(const float* __restrict__ x,
                                              const float* __restrict__ Wemb,
                                              const float* __restrict__ bemb,
                                              float* __restrict__ h) {
    int bs = blockIdx.x;            // 0..B*S-1
    int s  = bs & (SS - 1);
    int d  = threadIdx.x;           // 0..63
    const float* xr = x + bs * NF;
    float acc = bemb[d];
#pragma unroll
    for (int f = 0; f < NF; ++f) acc += xr[f] * Wemb[f * DD + d];
    int i = d >> 1;
    float div = expf((float)(2 * i) * (-9.210340371976184f / 64.0f));
    float ang = (float)s * div;
    float pe = (d & 1) ? cosf(ang) : sinf(ang);
    h[bs * DD + d] = acc + pe;
}

// ---------------- fused q,k,v projection (4 rows/block; f16 packed out) -----
__global__ __launch_bounds__(64) void k_qkv(const float* __restrict__ h,
                                            const float* __restrict__ Wq, const float* __restrict__ bq,
                                            const float* __restrict__ Wk, const float* __restrict__ bk,
                                            const float* __restrict__ Wv, const float* __restrict__ bv,
                                            hf2* __restrict__ qh, hf2* __restrict__ kvh, int l) {
    __shared__ float hrow[4][DD];
    int d   = threadIdx.x;
    int bs0 = blockIdx.x * 4;
#pragma unroll
    for (int r = 0; r < 4; ++r) hrow[r][d] = h[(bs0 + r) * DD + d];
    __syncthreads();
    const float* wq = Wq + l * DD * DD;
    const float* wk = Wk + l * DD * DD;
    const float* wv = Wv + l * DD * DD;
    float aq[4], ak[4], av[4];
    float bqv = bq[l * DD + d], bkv = bk[l * DD + d], bvv = bv[l * DD + d];
#pragma unroll
    for (int r = 0; r < 4; ++r) { aq[r] = bqv; ak[r] = bkv; av[r] = bvv; }
#pragma unroll 4
    for (int i = 0; i < DD; ++i) {
        float wqv = wq[i * DD + d], wkv = wk[i * DD + d], wvv = wv[i * DD + d];
#pragma unroll
        for (int r = 0; r < 4; ++r) {
            float hv = hrow[r][i];
            aq[r] += hv * wqv; ak[r] += hv * wkv; av[r] += hv * wvv;
        }
    }
    int hh = d >> 3, hd = d & 7;
    const float qs = 0.3535533906f;
    float aqp[4], akp[4];
#pragma unroll
    for (int r = 0; r < 4; ++r) { aqp[r] = __shfl_xor(aq[r], 1); akp[r] = __shfl_xor(ak[r], 1); }
    if ((hd & 1) == 0) {
#pragma unroll
        for (int r = 0; r < 4; ++r) {
            int bs = bs0 + r;
            int b = bs >> 10, s = bs & 1023;
            int bh = b * HH + hh;
            int bhs = (bh << 10) | s;
            qh[bhs * 4 + (hd >> 1)] = __builtin_amdgcn_cvt_pkrtz(aq[r] * qs, aqp[r] * qs);
            int tp = s >> 1, par = s & 1;
            kvh[(bh * 512 + tp) * 16 + par * 4 + (hd >> 1)] =
                __builtin_amdgcn_cvt_pkrtz(ak[r], akp[r]);
        }
    }
#pragma unroll
    for (int r = 0; r < 4; r += 2) {
        int bs = bs0 + r;
        int b = bs >> 10, s = bs & 1023;
        int bh = b * HH + hh;
        int tp = s >> 1;
        kvh[(bh * 512 + tp) * 16 + 8 + hd] = __builtin_amdgcn_cvt_pkrtz(av[r], av[r + 1]);
    }
}

// ---------------- attention: f16 dot2, kv chunk staged in LDS ---------------
// LDS broadcast reads land directly in VGPRs (no s->v movs for VOP3P dots).
__global__ __launch_bounds__(256) void k_attn(const hf2* __restrict__ qh,
                                              const float4* __restrict__ kvh4,
                                              float* __restrict__ Apart,   // [nch][BHS][8]
                                              float* __restrict__ lpart,   // [nch][BHS]
                                              int nch) {
    __shared__ float4 KVs[1024];      // up to 16 KB (tpc<=256)
    int bh  = blockIdx.x;             // 0..127
    int sg  = blockIdx.y & 3;
    int ch  = blockIdx.y >> 2;
    int tid = threadIdx.x;
    int s   = sg * 256 + tid;
    int tpc = 512 / nch;              // t-pairs per chunk
    const float4* kp = kvh4 + (size_t)(bh * 512 + ch * tpc) * 4;
    for (int i = tid; i < tpc * 4; i += 256) KVs[i] = kp[i];
    float4 qv = ((const float4*)qh)[(bh << 10) | s];
    hf2 q01 = ash2(qv.x), q23 = ash2(qv.y), q45 = ash2(qv.z), q67 = ash2(qv.w);
    hf2 one2 = __builtin_amdgcn_cvt_pkrtz(1.f, 1.f);
    float ls = 0.f;
    float A[8] = {0,0,0,0,0,0,0,0};
    __syncthreads();
#pragma unroll 2
    for (int t = 0; t < tpc; ++t) {
        float4 f0 = KVs[4*t], f1 = KVs[4*t+1], f2 = KVs[4*t+2], f3 = KVs[4*t+3];
        float sc0 = __builtin_amdgcn_fdot2(q67, ash2(f0.w),
                    __builtin_amdgcn_fdot2(q45, ash2(f0.z),
                    __builtin_amdgcn_fdot2(q23, ash2(f0.y),
                    __builtin_amdgcn_fdot2(q01, ash2(f0.x), 0.f, false), false), false), false);
        float sc1 = __builtin_amdgcn_fdot2(q67, ash2(f1.w),
                    __builtin_amdgcn_fdot2(q45, ash2(f1.z),
                    __builtin_amdgcn_fdot2(q23, ash2(f1.y),
                    __builtin_amdgcn_fdot2(q01, ash2(f1.x), 0.f, false), false), false), false);
        float p0 = __expf(sc0), p1 = __expf(sc1);
        hf2 pp = __builtin_amdgcn_cvt_pkrtz(p0, p1);
        ls   = __builtin_amdgcn_fdot2(pp, one2,       ls,   false);
        A[0] = __builtin_amdgcn_fdot2(pp, ash2(f2.x), A[0], false);
        A[1] = __builtin_amdgcn_fdot2(pp, ash2(f2.y), A[1], false);
        A[2] = __builtin_amdgcn_fdot2(pp, ash2(f2.z), A[2], false);
        A[3] = __builtin_amdgcn_fdot2(pp, ash2(f2.w), A[3], false);
        A[4] = __builtin_amdgcn_fdot2(pp, ash2(f3.x), A[4], false);
        A[5] = __builtin_amdgcn_fdot2(pp, ash2(f3.y), A[5], false);
        A[6] = __builtin_amdgcn_fdot2(pp, ash2(f3.z), A[6], false);
        A[7] = __builtin_amdgcn_fdot2(pp, ash2(f3.w), A[7], false);
    }
    int bhs = (bh << 10) | s;
    float* arow = Apart + (((size_t)ch << 17) + bhs) * 8;
    ((float4*)arow)[0] = make_float4(A[0], A[1], A[2], A[3]);
    ((float4*)arow)[1] = make_float4(A[4], A[5], A[6], A[7]);
    lpart[((size_t)ch << 17) + bhs] = ls;
}

// ---------------- attention combine + O projection + residual + layernorm ----
__global__ __launch_bounds__(64) void k_projln(const float* __restrict__ Apart,
                                               const float* __restrict__ lpart,
                                               const float* __restrict__ Wo, const float* __restrict__ bo,
                                               const float* __restrict__ g, const float* __restrict__ bp,
                                               float* __restrict__ h, int l, int nch) {
    __shared__ float orow[4][DD];
    int d   = threadIdx.x;
    int bs0 = blockIdx.x * 4;
    int hh = d >> 3, hd = d & 7;
#pragma unroll
    for (int r = 0; r < 4; ++r) {
        int bs = bs0 + r;
        int b = bs >> 10, s = bs & 1023;
        int bhs = ((b * HH + hh) << 10) | s;
        float a = 0.f, lt = 0.f;
        for (int ch = 0; ch < nch; ++ch) {
            a  += Apart[(((size_t)ch << 17) + bhs) * 8 + hd];
            lt += lpart[((size_t)ch << 17) + bhs];
        }
        orow[r][d] = a / lt;
    }
    __syncthreads();
    const float* w = Wo + l * DD * DD;
    float bias = bo[l * DD + d];
    float acc[4] = {bias, bias, bias, bias};
#pragma unroll 4
    for (int i = 0; i < DD; ++i) {
        float wv = w[i * DD + d];
        acc[0] += orow[0][i]*wv; acc[1] += orow[1][i]*wv;
        acc[2] += orow[2][i]*wv; acc[3] += orow[3][i]*wv;
    }
    float gg = g[l * DD + d], bb = bp[l * DD + d];
#pragma unroll
    for (int r = 0; r < 4; ++r) {
        int bs = bs0 + r;
        float a = acc[r] + h[bs * DD + d];
        float sum = a;
        for (int off = 32; off; off >>= 1) sum += __shfl_xor(sum, off);
        float mean = sum * (1.f / 64.f);
        float dx = a - mean;
        float vs = dx * dx;
        for (int off = 32; off; off >>= 1) vs += __shfl_xor(vs, off);
        float rstd = rsqrtf(vs * (1.f / 64.f) + 1e-5f);
        h[bs * DD + d] = dx * rstd * gg + bb;
    }
}

// ---------------- fused FFN: relu(h W1 + b1) W2 + b2 + residual + LN --------
// 128 threads, 4 rows/block. Phase A: thread=f computes ff into LDS.
// Phase B: wave 0 (rows 0,1), wave 1 (rows 2,3); LN shuffles stay in-wave.
__global__ __launch_bounds__(128) void k_ffn(const float* __restrict__ Wf1, const float* __restrict__ bf1,
                                             const float* __restrict__ Wf2, const float* __restrict__ bf2,
                                             const float* __restrict__ g, const float* __restrict__ bp,
                                             float* __restrict__ h, int l) {
    __shared__ float hrow[4][DD];
    __shared__ float frow[4][FFD];
    int t   = threadIdx.x;
    int bs0 = blockIdx.x * 4;
#pragma unroll
    for (int e = t; e < 4 * DD; e += 128) ((float*)hrow)[e] = h[bs0 * DD + e];
    __syncthreads();
    {
        const float* w = Wf1 + l * DD * FFD;
        float bv = bf1[l * FFD + t];
        float a0 = bv, a1 = bv, a2 = bv, a3 = bv;
#pragma unroll 4
        for (int i = 0; i < DD; ++i) {
            float wv = w[i * FFD + t];
            a0 += hrow[0][i]*wv; a1 += hrow[1][i]*wv;
            a2 += hrow[2][i]*wv; a3 += hrow[3][i]*wv;
        }
        frow[0][t] = fmaxf(a0, 0.f); frow[1][t] = fmaxf(a1, 0.f);
        frow[2][t] = fmaxf(a2, 0.f); frow[3][t] = fmaxf(a3, 0.f);
    }
    __syncthreads();
    {
        int d = t & 63, half = t >> 6;
        int r0 = half * 2, r1 = r0 + 1;
        const float* w = Wf2 + l * FFD * DD;
        float bias = bf2[l * DD + d];
        float acc0 = bias, acc1 = bias;
#pragma unroll 4
        for (int i = 0; i < FFD; ++i) {
            float wv = w[i * DD + d];
            acc0 += frow[r0][i] * wv;
            acc1 += frow[r1][i] * wv;
        }
        float gg = g[l * DD + d], bb = bp[l * DD + d];
        float accs[2] = {acc0, acc1};
#pragma unroll
        for (int rr = 0; rr < 2; ++rr) {
            int r = r0 + rr;
            float a = accs[rr] + hrow[r][d];
            float sum = a;
            for (int off = 32; off; off >>= 1) sum += __shfl_xor(sum, off);
            float mean = sum * (1.f / 64.f);
            float dx = a - mean;
            float vs = dx * dx;
            for (int off = 32; off; off >>= 1) vs += __shfl_xor(vs, off);
            float rstd = rsqrtf(vs * (1.f / 64.f) + 1e-5f);
            h[(bs0 + r) * DD + d] = dx * rstd * gg + bb;
        }
    }
}

// ---------------- mean pool over sequence (8-way split) ----------------
__global__ __launch_bounds__(64) void k_pool(const float* __restrict__ h, float* __restrict__ pp) {
    int b = blockIdx.x, c = blockIdx.y, d = threadIdx.x;
    const float* hp = h + (b * SS + c * 128) * DD + d;
    float acc = 0.f;
#pragma unroll 8
    for (int s = 0; s < 128; ++s) acc += hp[s * DD];
    pp[(b * 8 + c) * DD + d] = acc;
}

// ---------------- fused tail: head (angles) + quantum circuit + eigensolver -
// 16 blocks x 64 threads. angles and psi handed off through LDS.
__global__ __launch_bounds__(64) void k_tail(const float* __restrict__ pp,
                                             const float* __restrict__ Wp1, const float* __restrict__ bp1,
                                             const float* __restrict__ Wp2, const float* __restrict__ bp2,
                                             const float* __restrict__ qw,
                                             float* __restrict__ out) {
    __shared__ float pool_s[DD];
    __shared__ float hid[32];
    __shared__ float ang_s[NQ];
    __shared__ float2 Ps2[256];
    int b = blockIdx.x; int L = threadIdx.x;

    // ---- head ----
    {
        float acc = 0.f;
#pragma unroll
        for (int c = 0; c < 8; ++c) acc += pp[(b * 8 + c) * DD + L];
        pool_s[L] = acc * (1.f / 1024.f);
    }
    __syncthreads();
    if (L < 32) {
        float a = bp1[L];
        for (int i = 0; i < DD; ++i) a += pool_s[i] * Wp1[i * 32 + L];
        hid[L] = fmaxf(a, 0.f);
    }
    __syncthreads();
    if (L < NQ) {
        float a = bp2[L];
        for (int j = 0; j < 32; ++j) a += hid[j] * Wp2[j * NQ + L];
        ang_s[L] = tanhf(a) * 3.14159265358979f;
    }
    __syncthreads();

    // ---- quantum circuit ----
    float ar[4], ai[4];
#pragma unroll
    for (int r = 0; r < 4; ++r) { ar[r] = 0.f; ai[r] = 0.f; }
    if (L == 0) ar[0] = 1.f;

    for (int l = 0; l < QLAY; ++l) {
#pragma unroll
        for (int w = 0; w < NQ; ++w) {
            int p = 7 - w;
            float half = 0.5f * ang_s[w];
            float c = cosf(half), s = sinf(half);
            if (p == 7) {
#pragma unroll
                for (int lo = 0; lo < 2; ++lo) {
                    int hi = lo + 2;
                    float r0=ar[lo], m0=ai[lo], r1=ar[hi], m1=ai[hi];
                    ar[lo] = c*r0 + s*m1;  ai[lo] = c*m0 - s*r1;
                    ar[hi] = c*r1 + s*m0;  ai[hi] = c*m1 - s*r0;
                }
            } else if (p == 6) {
#pragma unroll
                for (int base = 0; base < 4; base += 2) {
                    int lo = base, hi = base + 1;
                    float r0=ar[lo], m0=ai[lo], r1=ar[hi], m1=ai[hi];
                    ar[lo] = c*r0 + s*m1;  ai[lo] = c*m0 - s*r1;
                    ar[hi] = c*r1 + s*m0;  ai[hi] = c*m1 - s*r0;
                }
            } else {
                int mask = 1 << p;
#pragma unroll
                for (int r = 0; r < 4; ++r) {
                    float pre = __shfl_xor(ar[r], mask);
                    float pim = __shfl_xor(ai[r], mask);
                    float nr = c*ar[r] + s*pim;
                    float ni = c*ai[r] - s*pre;
                    ar[r] = nr; ai[r] = ni;
                }
            }
        }
#pragma unroll
        for (int w = 0; w < NQ; ++w) {
            const float* p3 = qw + (l * NQ + w) * 3;
            float phi = p3[0], th = p3[1], om = p3[2];
            float ct = cosf(0.5f * th), st = sinf(0.5f * th);
            float al = 0.5f * (phi + om), be = 0.5f * (phi - om);
            float ca = cosf(al), sa = sinf(al), cb = cosf(be), sb = sinf(be);
            float u00r =  ct * ca, u00i = -ct * sa;
            float u01r = -st * cb, u01i = -st * sb;
            float u10r =  st * cb, u10i = -st * sb;
            float u11r =  ct * ca, u11i =  ct * sa;
            int p = 7 - w;
            if (p >= 6) {
#pragma unroll
                for (int pi_ = 0; pi_ < 2; ++pi_) {
                    int lo = (p == 7) ? pi_ : pi_ * 2;
                    int hi = (p == 7) ? pi_ + 2 : pi_ * 2 + 1;
                    float r0=ar[lo], m0=ai[lo], r1=ar[hi], m1=ai[hi];
                    ar[lo] = u00r*r0 - u00i*m0 + u01r*r1 - u01i*m1;
                    ai[lo] = u00r*m0 + u00i*r0 + u01r*m1 + u01i*r1;
                    ar[hi] = u10r*r0 - u10i*m0 + u11r*r1 - u11i*m1;
                    ai[hi] = u10r*m0 + u10i*r0 + u11r*m1 + u11i*r1;
                }
            } else {
                int mask = 1 << p;
                int bit = (L >> p) & 1;
                float car = bit ? u11r : u00r, cai = bit ? u11i : u00i;
                float cpr = bit ? u10r : u01r, cpi = bit ? u10i : u01i;
#pragma unroll
                for (int r = 0; r < 4; ++r) {
                    float pre = __shfl_xor(ar[r], mask);
                    float pim = __shfl_xor(ai[r], mask);
                    float nr = car*ar[r] - cai*ai[r] + cpr*pre - cpi*pim;
                    float ni = car*ai[r] + cai*ar[r] + cpr*pim + cpi*pre;
                    ar[r] = nr; ai[r] = ni;
                }
            }
        }
        { float t0=ar[2]; ar[2]=ar[3]; ar[3]=t0; t0=ai[2]; ai[2]=ai[3]; ai[3]=t0; }
        ar[1]=__shfl_xor(ar[1],32); ai[1]=__shfl_xor(ai[1],32);
        ar[3]=__shfl_xor(ar[3],32); ai[3]=__shfl_xor(ai[3],32);
#pragma unroll
        for (int w = 2; w <= 6; ++w) {
            int pc = 7 - w, pt = 6 - w;
            int tm = 1 << pt;
            bool ctrl = (L >> pc) & 1;
#pragma unroll
            for (int r = 0; r < 4; ++r) {
                float swr = __shfl_xor(ar[r], tm);
                float swi = __shfl_xor(ai[r], tm);
                ar[r] = ctrl ? swr : ar[r];
                ai[r] = ctrl ? swi : ai[r];
            }
        }
        {
            bool ctrl = L & 1;
            float n0r = ctrl ? ar[2] : ar[0], n2r = ctrl ? ar[0] : ar[2];
            float n0i = ctrl ? ai[2] : ai[0], n2i = ctrl ? ai[0] : ai[2];
            float n1r = ctrl ? ar[3] : ar[1], n3r = ctrl ? ar[1] : ar[3];
            float n1i = ctrl ? ai[3] : ai[1], n3i = ctrl ? ai[1] : ai[3];
            ar[0]=n0r; ar[1]=n1r; ar[2]=n2r; ar[3]=n3r;
            ai[0]=n0i; ai[1]=n1i; ai[2]=n2i; ai[3]=n3i;
        }
    }

    // ---- <Z_w>, w=0..2 ----
    {
        float p0 = ar[0]*ar[0]+ai[0]*ai[0];
        float p1 = ar[1]*ar[1]+ai[1]*ai[1];
        float p2 = ar[2]*ar[2]+ai[2]*ai[2];
        float p3 = ar[3]*ar[3]+ai[3]*ai[3];
        float z0 = p0 + p1 - p2 - p3;
        float z1 = p0 - p1 + p2 - p3;
        float zs = p0 + p1 + p2 + p3;
        float z2 = (L & 32) ? -zs : zs;
#pragma unroll
        for (int off = 1; off < 64; off <<= 1) {
            z0 += __shfl_xor(z0, off);
            z1 += __shfl_xor(z1, off);
            z2 += __shfl_xor(z2, off);
        }
        if (L == 0) {
            out[b * NC + 0] = z0;
            out[b * NC + 1] = z1;
            out[b * NC + 2] = z2;
        }
    }

    // ---- hand off psi through LDS, redistribute to column layout ----
#pragma unroll
    for (int r = 0; r < 4; ++r) Ps2[(r << 6) | L] = make_float2(ar[r], ai[r]);
    __syncthreads();
    int c   = L >> 2;                 // my column
    int seg = L & 3;                  // my segment (4 elements)
    float gr[4], gi[4];
#pragma unroll
    for (int j = 0; j < 4; ++j) {
        float2 t = Ps2[(seg * 4 + j) * 16 + c];
        gr[j] = t.x; gi[j] = t.y;
    }

    // ---- one-sided Jacobi, 4 lanes per column, shfl exchange ----
    for (int sweep = 0; sweep < NSWEEP; ++sweep) {
        for (int rd = 0; rd < 15; ++rd) {
            int q;
            if (c == 15) q = rd;
            else {
                int u = c - rd; if (u < 0) u += 15;
                if (u == 0) q = 15;
                else { q = rd + 15 - u; if (q >= 15) q -= 15; }
            }
            int pl = (q << 2) | seg;
            float pgr[4], pgi[4];
#pragma unroll
            for (int j = 0; j < 4; ++j) {
                pgr[j] = __shfl(gr[j], pl);
                pgi[j] = __shfl(gi[j], pl);
            }
            float alm = 0.f, d = 0.f, e = 0.f;
#pragma unroll
            for (int j = 0; j < 4; ++j) {
                alm += gr[j]*gr[j] + gi[j]*gi[j];
                d   += gr[j]*pgr[j] + gi[j]*pgi[j];   // Re(mine^H partner)
                e   += gr[j]*pgi[j] - gi[j]*pgr[j];   // Im(mine^H partner)
            }
            alm += __shfl_xor(alm, 1); d += __shfl_xor(d, 1); e += __shfl_xor(e, 1);
            alm += __shfl_xor(alm, 2); d += __shfl_xor(d, 2); e += __shfl_xor(e, 2);
            float bep = __shfl(alm, pl);              // |partner|^2
            float g2 = d*d + e*e;
            float cth = 1.f, sth = 0.f, cph = 1.f, sph = 0.f;
            if (g2 > 1e-26f) {
                float gn = sqrtf(g2);
                float ginv = 1.f / gn;
                cph = d * ginv; sph = -e * ginv;       // conj(gamma)/|gamma|
                float tau = (alm - bep) * (0.5f * ginv);
                float t = ((tau >= 0.f) ? 1.f : -1.f) / (fabsf(tau) + sqrtf(1.f + tau*tau));
                cth = rsqrtf(1.f + t*t);
                sth = t * cth;
            }
#pragma unroll
            for (int j = 0; j < 4; ++j) {
                float er = cph*pgr[j] - sph*pgi[j];
                float ei = cph*pgi[j] + sph*pgr[j];
                gr[j] = cth * gr[j] + sth * er;
                gi[j] = cth * gi[j] + sth * ei;
            }
        }
    }

    float lam = 0.f;
#pragma unroll
    for (int j = 0; j < 4; ++j) lam += gr[j]*gr[j] + gi[j]*gi[j];
    lam += __shfl_xor(lam, 1);
    lam += __shfl_xor(lam, 2);                        // full column norm^2
    float ev = fminf(fmaxf(lam, 1e-10f), 1.0f);
    float term = -ev * logf(ev);
#pragma unroll
    for (int off = 4; off < 64; off <<= 1) term += __shfl_xor(term, off);
    if (L == 0) out[BB * NC + b] = term;
}

extern "C" void kernel_launch(void* const* d_in, const int* in_sizes, int n_in,
                              void* d_out, int out_size, void* d_ws, size_t ws_size,
                              hipStream_t stream) {
    const float* x    = (const float*)d_in[0];
    const float* Wemb = (const float*)d_in[1];
    const float* bemb = (const float*)d_in[2];
    const float* Wq   = (const float*)d_in[3];
    const float* bq   = (const float*)d_in[4];
    const float* Wk   = (const float*)d_in[5];
    const float* bk   = (const float*)d_in[6];
    const float* Wv   = (const float*)d_in[7];
    const float* bv   = (const float*)d_in[8];
    const float* Wo   = (const float*)d_in[9];
    const float* bo   = (const float*)d_in[10];
    const float* ln1g = (const float*)d_in[11];
    const float* ln1b = (const float*)d_in[12];
    const float* ln2g = (const float*)d_in[13];
    const float* ln2b = (const float*)d_in[14];
    const float* Wf1  = (const float*)d_in[15];
    const float* bf1  = (const float*)d_in[16];
    const float* Wf2  = (const float*)d_in[17];
    const float* bf2  = (const float*)d_in[18];
    const float* Wp1  = (const float*)d_in[19];
    const float* bp1  = (const float*)d_in[20];
    const float* Wp2  = (const float*)d_in[21];
    const float* bp2  = (const float*)d_in[22];
    const float* qwts = (const float*)d_in[23];
    float* out = (float*)d_out;

    const size_t M = 1u << 20;           // 1M floats = B*S*D
    auto needF = [&](int nch) {
        return (size_t)(4.5 * M) + (size_t)nch * M + (size_t)nch * BHS_TOT + BB * 8 * DD + 16384;
    };
    int nch = (ws_size >= needF(4) * sizeof(float)) ? 4 : 2;

    float* ws     = (float*)d_ws;
    float* h      = ws;                               // 1M
    hf2*   qh     = (hf2*)(ws + M);                   // 0.5M floats
    hf2*   kvh    = (hf2*)(ws + M + M / 2);           // 1M floats
    float* Apart  = ws + (M * 9) / 2;                 // nch*M
    float* lpart  = Apart + (size_t)nch * M;          // nch*BHS_TOT
    float* pp     = lpart + (size_t)nch * BHS_TOT;    // [16][8][64]

    k_embed<<<BB * SS, 64, 0, stream>>>(x, Wemb, bemb, h);
    for (int l = 0; l < NLAYER; ++l) {
        k_qkv<<<BB * SS / 4, 64, 0, stream>>>(h, Wq, bq, Wk, bk, Wv, bv, qh, kvh, l);
        k_attn<<<dim3(BB * HH, 4 * nch), 256, 0, stream>>>(qh, (const float4*)kvh, Apart, lpart, nch);
        k_projln<<<BB * SS / 4, 64, 0, stream>>>(Apart, lpart, Wo, bo, ln1g, ln1b, h, l, nch);
        k_ffn<<<BB * SS / 4, 128, 0, stream>>>(Wf1, bf1, Wf2, bf2, ln2g, ln2b, h, l);
    }
    k_pool<<<dim3(BB, 8), 64, 0, stream>>>(h, pp);
    k_tail<<<BB, 64, 0, stream>>>(pp, Wp1, bp1, Wp2, bp2, qwts, out);
}

// Round 15
// 365.267 us; speedup vs baseline: 1.3254x; 1.0780x over previous
//
#include <hip/hip_runtime.h>
#include <math.h>

#define BB 16
#define SS 1024
#define NF 5
#define DD 64
#define HH 8
#define HDIM 8
#define NLAYER 2
#define FFD 128
#define NQ 8
#define QLAY 3
#define NC 3
#define NSWEEP 5
#define BHS_TOT (BB * HH * SS)   // 131072 = 1<<17

typedef __fp16 hf2 __attribute__((ext_vector_type(2)));
__device__ inline hf2 ash2(float f) { union { float f; hf2 h; } u; u.f = f; return u.h; }

// ---------------- embed + positional encoding ----------------
__global__ __launch_bounds__(64) void k_embed(const float* __restrict__ x,
                                              const float* __restrict__ Wemb,
                                              const float* __restrict__ bemb,
                                              float* __restrict__ h) {
    int bs = blockIdx.x;            // 0..B*S-1
    int s  = bs & (SS - 1);
    int d  = threadIdx.x;           // 0..63
    const float* xr = x + bs * NF;
    float acc = bemb[d];
#pragma unroll
    for (int f = 0; f < NF; ++f) acc += xr[f] * Wemb[f * DD + d];
    int i = d >> 1;
    float div = expf((float)(2 * i) * (-9.210340371976184f / 64.0f));
    float ang = (float)s * div;
    float pe = (d & 1) ? cosf(ang) : sinf(ang);
    h[bs * DD + d] = acc + pe;
}

// ---------------- fused q,k,v projection (4 rows/block; f16 packed out) -----
__global__ __launch_bounds__(64) void k_qkv(const float* __restrict__ h,
                                            const float* __restrict__ Wq, const float* __restrict__ bq,
                                            const float* __restrict__ Wk, const float* __restrict__ bk,
                                            const float* __restrict__ Wv, const float* __restrict__ bv,
                                            hf2* __restrict__ qh, hf2* __restrict__ kvh, int l) {
    __shared__ float hrow[4][DD];
    int d   = threadIdx.x;
    int bs0 = blockIdx.x * 4;
#pragma unroll
    for (int r = 0; r < 4; ++r) hrow[r][d] = h[(bs0 + r) * DD + d];
    __syncthreads();
    const float* wq = Wq + l * DD * DD;
    const float* wk = Wk + l * DD * DD;
    const float* wv = Wv + l * DD * DD;
    float aq[4], ak[4], av[4];
    float bqv = bq[l * DD + d], bkv = bk[l * DD + d], bvv = bv[l * DD + d];
#pragma unroll
    for (int r = 0; r < 4; ++r) { aq[r] = bqv; ak[r] = bkv; av[r] = bvv; }
#pragma unroll 4
    for (int i = 0; i < DD; ++i) {
        float wqv = wq[i * DD + d], wkv = wk[i * DD + d], wvv = wv[i * DD + d];
#pragma unroll
        for (int r = 0; r < 4; ++r) {
            float hv = hrow[r][i];
            aq[r] += hv * wqv; ak[r] += hv * wkv; av[r] += hv * wvv;
        }
    }
    int hh = d >> 3, hd = d & 7;
    const float qs = 0.3535533906f;
    float aqp[4], akp[4];
#pragma unroll
    for (int r = 0; r < 4; ++r) { aqp[r] = __shfl_xor(aq[r], 1); akp[r] = __shfl_xor(ak[r], 1); }
    if ((hd & 1) == 0) {
#pragma unroll
        for (int r = 0; r < 4; ++r) {
            int bs = bs0 + r;
            int b = bs >> 10, s = bs & 1023;
            int bh = b * HH + hh;
            int bhs = (bh << 10) | s;
            qh[bhs * 4 + (hd >> 1)] = __builtin_amdgcn_cvt_pkrtz(aq[r] * qs, aqp[r] * qs);
            int tp = s >> 1, par = s & 1;
            kvh[(bh * 512 + tp) * 16 + par * 4 + (hd >> 1)] =
                __builtin_amdgcn_cvt_pkrtz(ak[r], akp[r]);
        }
    }
#pragma unroll
    for (int r = 0; r < 4; r += 2) {
        int bs = bs0 + r;
        int b = bs >> 10, s = bs & 1023;
        int bh = b * HH + hh;
        int tp = s >> 1;
        kvh[(bh * 512 + tp) * 16 + 8 + hd] = __builtin_amdgcn_cvt_pkrtz(av[r], av[r + 1]);
    }
}

// ---------------- attention: f16 dot2, kv chunk staged in LDS ---------------
__global__ __launch_bounds__(256) void k_attn(const hf2* __restrict__ qh,
                                              const float4* __restrict__ kvh4,
                                              float* __restrict__ Apart,   // [nch][BHS][8]
                                              float* __restrict__ lpart,   // [nch][BHS]
                                              int nch) {
    __shared__ float4 KVs[1024];      // up to 16 KB (tpc<=256)
    int bh  = blockIdx.x;             // 0..127
    int sg  = blockIdx.y & 3;
    int ch  = blockIdx.y >> 2;
    int tid = threadIdx.x;
    int s   = sg * 256 + tid;
    int tpc = 512 / nch;              // t-pairs per chunk
    const float4* kp = kvh4 + (size_t)(bh * 512 + ch * tpc) * 4;
    for (int i = tid; i < tpc * 4; i += 256) KVs[i] = kp[i];
    float4 qv = ((const float4*)qh)[(bh << 10) | s];
    hf2 q01 = ash2(qv.x), q23 = ash2(qv.y), q45 = ash2(qv.z), q67 = ash2(qv.w);
    hf2 one2 = __builtin_amdgcn_cvt_pkrtz(1.f, 1.f);
    float ls = 0.f;
    float A[8] = {0,0,0,0,0,0,0,0};
    __syncthreads();
#pragma unroll 2
    for (int t = 0; t < tpc; ++t) {
        float4 f0 = KVs[4*t], f1 = KVs[4*t+1], f2 = KVs[4*t+2], f3 = KVs[4*t+3];
        float sc0 = __builtin_amdgcn_fdot2(q67, ash2(f0.w),
                    __builtin_amdgcn_fdot2(q45, ash2(f0.z),
                    __builtin_amdgcn_fdot2(q23, ash2(f0.y),
                    __builtin_amdgcn_fdot2(q01, ash2(f0.x), 0.f, false), false), false), false);
        float sc1 = __builtin_amdgcn_fdot2(q67, ash2(f1.w),
                    __builtin_amdgcn_fdot2(q45, ash2(f1.z),
                    __builtin_amdgcn_fdot2(q23, ash2(f1.y),
                    __builtin_amdgcn_fdot2(q01, ash2(f1.x), 0.f, false), false), false), false);
        float p0 = __expf(sc0), p1 = __expf(sc1);
        hf2 pp = __builtin_amdgcn_cvt_pkrtz(p0, p1);
        ls   = __builtin_amdgcn_fdot2(pp, one2,       ls,   false);
        A[0] = __builtin_amdgcn_fdot2(pp, ash2(f2.x), A[0], false);
        A[1] = __builtin_amdgcn_fdot2(pp, ash2(f2.y), A[1], false);
        A[2] = __builtin_amdgcn_fdot2(pp, ash2(f2.z), A[2], false);
        A[3] = __builtin_amdgcn_fdot2(pp, ash2(f2.w), A[3], false);
        A[4] = __builtin_amdgcn_fdot2(pp, ash2(f3.x), A[4], false);
        A[5] = __builtin_amdgcn_fdot2(pp, ash2(f3.y), A[5], false);
        A[6] = __builtin_amdgcn_fdot2(pp, ash2(f3.z), A[6], false);
        A[7] = __builtin_amdgcn_fdot2(pp, ash2(f3.w), A[7], false);
    }
    int bhs = (bh << 10) | s;
    float* arow = Apart + (((size_t)ch << 17) + bhs) * 8;
    ((float4*)arow)[0] = make_float4(A[0], A[1], A[2], A[3]);
    ((float4*)arow)[1] = make_float4(A[4], A[5], A[6], A[7]);
    lpart[((size_t)ch << 17) + bhs] = ls;
}

// ---------------- attention combine + O projection + residual + layernorm ----
__global__ __launch_bounds__(64) void k_projln(const float* __restrict__ Apart,
                                               const float* __restrict__ lpart,
                                               const float* __restrict__ Wo, const float* __restrict__ bo,
                                               const float* __restrict__ g, const float* __restrict__ bp,
                                               float* __restrict__ h, int l, int nch) {
    __shared__ float orow[4][DD];
    int d   = threadIdx.x;
    int bs0 = blockIdx.x * 4;
    int hh = d >> 3, hd = d & 7;
#pragma unroll
    for (int r = 0; r < 4; ++r) {
        int bs = bs0 + r;
        int b = bs >> 10, s = bs & 1023;
        int bhs = ((b * HH + hh) << 10) | s;
        float a = 0.f, lt = 0.f;
        for (int ch = 0; ch < nch; ++ch) {
            a  += Apart[(((size_t)ch << 17) + bhs) * 8 + hd];
            lt += lpart[((size_t)ch << 17) + bhs];
        }
        orow[r][d] = a / lt;
    }
    __syncthreads();
    const float* w = Wo + l * DD * DD;
    float bias = bo[l * DD + d];
    float acc[4] = {bias, bias, bias, bias};
#pragma unroll 4
    for (int i = 0; i < DD; ++i) {
        float wv = w[i * DD + d];
        acc[0] += orow[0][i]*wv; acc[1] += orow[1][i]*wv;
        acc[2] += orow[2][i]*wv; acc[3] += orow[3][i]*wv;
    }
    float gg = g[l * DD + d], bb = bp[l * DD + d];
#pragma unroll
    for (int r = 0; r < 4; ++r) {
        int bs = bs0 + r;
        float a = acc[r] + h[bs * DD + d];
        float sum = a;
        for (int off = 32; off; off >>= 1) sum += __shfl_xor(sum, off);
        float mean = sum * (1.f / 64.f);
        float dx = a - mean;
        float vs = dx * dx;
        for (int off = 32; off; off >>= 1) vs += __shfl_xor(vs, off);
        float rstd = rsqrtf(vs * (1.f / 64.f) + 1e-5f);
        h[bs * DD + d] = dx * rstd * gg + bb;
    }
}

// ---------------- fused FFN: relu(h W1 + b1) W2 + b2 + residual + LN --------
__global__ __launch_bounds__(128) void k_ffn(const float* __restrict__ Wf1, const float* __restrict__ bf1,
                                             const float* __restrict__ Wf2, const float* __restrict__ bf2,
                                             const float* __restrict__ g, const float* __restrict__ bp,
                                             float* __restrict__ h, int l) {
    __shared__ float hrow[4][DD];
    __shared__ float frow[4][FFD];
    int t   = threadIdx.x;
    int bs0 = blockIdx.x * 4;
#pragma unroll
    for (int e = t; e < 4 * DD; e += 128) ((float*)hrow)[e] = h[bs0 * DD + e];
    __syncthreads();
    {
        const float* w = Wf1 + l * DD * FFD;
        float bv = bf1[l * FFD + t];
        float a0 = bv, a1 = bv, a2 = bv, a3 = bv;
#pragma unroll 4
        for (int i = 0; i < DD; ++i) {
            float wv = w[i * FFD + t];
            a0 += hrow[0][i]*wv; a1 += hrow[1][i]*wv;
            a2 += hrow[2][i]*wv; a3 += hrow[3][i]*wv;
        }
        frow[0][t] = fmaxf(a0, 0.f); frow[1][t] = fmaxf(a1, 0.f);
        frow[2][t] = fmaxf(a2, 0.f); frow[3][t] = fmaxf(a3, 0.f);
    }
    __syncthreads();
    {
        int d = t & 63, half = t >> 6;
        int r0 = half * 2, r1 = r0 + 1;
        const float* w = Wf2 + l * FFD * DD;
        float bias = bf2[l * DD + d];
        float acc0 = bias, acc1 = bias;
#pragma unroll 4
        for (int i = 0; i < FFD; ++i) {
            float wv = w[i * DD + d];
            acc0 += frow[r0][i] * wv;
            acc1 += frow[r1][i] * wv;
        }
        float gg = g[l * DD + d], bb = bp[l * DD + d];
        float accs[2] = {acc0, acc1};
#pragma unroll
        for (int rr = 0; rr < 2; ++rr) {
            int r = r0 + rr;
            float a = accs[rr] + hrow[r][d];
            float sum = a;
            for (int off = 32; off; off >>= 1) sum += __shfl_xor(sum, off);
            float mean = sum * (1.f / 64.f);
            float dx = a - mean;
            float vs = dx * dx;
            for (int off = 32; off; off >>= 1) vs += __shfl_xor(vs, off);
            float rstd = rsqrtf(vs * (1.f / 64.f) + 1e-5f);
            h[(bs0 + r) * DD + d] = dx * rstd * gg + bb;
        }
    }
}

// ---------------- mean pool over sequence (8-way split) ----------------
__global__ __launch_bounds__(64) void k_pool(const float* __restrict__ h, float* __restrict__ pp) {
    int b = blockIdx.x, c = blockIdx.y, d = threadIdx.x;
    const float* hp = h + (b * SS + c * 128) * DD + d;
    float acc = 0.f;
#pragma unroll 8
    for (int s = 0; s < 128; ++s) acc += hp[s * DD];
    pp[(b * 8 + c) * DD + d] = acc;
}

// ---------------- fused tail: head (angles) + quantum circuit + eigensolver -
// Eigensolver: XOR-tournament one-sided Jacobi (m=1..15 covers every pair),
// partner alm folded into the shuffle group, incremental norm tracking.
__global__ __launch_bounds__(64) void k_tail(const float* __restrict__ pp,
                                             const float* __restrict__ Wp1, const float* __restrict__ bp1,
                                             const float* __restrict__ Wp2, const float* __restrict__ bp2,
                                             const float* __restrict__ qw,
                                             float* __restrict__ out) {
    __shared__ float pool_s[DD];
    __shared__ float hid[32];
    __shared__ float ang_s[NQ];
    __shared__ float2 Ps2[256];
    int b = blockIdx.x; int L = threadIdx.x;

    // ---- head ----
    {
        float acc = 0.f;
#pragma unroll
        for (int c = 0; c < 8; ++c) acc += pp[(b * 8 + c) * DD + L];
        pool_s[L] = acc * (1.f / 1024.f);
    }
    __syncthreads();
    if (L < 32) {
        float a = bp1[L];
        for (int i = 0; i < DD; ++i) a += pool_s[i] * Wp1[i * 32 + L];
        hid[L] = fmaxf(a, 0.f);
    }
    __syncthreads();
    if (L < NQ) {
        float a = bp2[L];
        for (int j = 0; j < 32; ++j) a += hid[j] * Wp2[j * NQ + L];
        ang_s[L] = tanhf(a) * 3.14159265358979f;
    }
    __syncthreads();

    // ---- quantum circuit ----
    float ar[4], ai[4];
#pragma unroll
    for (int r = 0; r < 4; ++r) { ar[r] = 0.f; ai[r] = 0.f; }
    if (L == 0) ar[0] = 1.f;

    for (int l = 0; l < QLAY; ++l) {
#pragma unroll
        for (int w = 0; w < NQ; ++w) {
            int p = 7 - w;
            float half = 0.5f * ang_s[w];
            float c = cosf(half), s = sinf(half);
            if (p == 7) {
#pragma unroll
                for (int lo = 0; lo < 2; ++lo) {
                    int hi = lo + 2;
                    float r0=ar[lo], m0=ai[lo], r1=ar[hi], m1=ai[hi];
                    ar[lo] = c*r0 + s*m1;  ai[lo] = c*m0 - s*r1;
                    ar[hi] = c*r1 + s*m0;  ai[hi] = c*m1 - s*r0;
                }
            } else if (p == 6) {
#pragma unroll
                for (int base = 0; base < 4; base += 2) {
                    int lo = base, hi = base + 1;
                    float r0=ar[lo], m0=ai[lo], r1=ar[hi], m1=ai[hi];
                    ar[lo] = c*r0 + s*m1;  ai[lo] = c*m0 - s*r1;
                    ar[hi] = c*r1 + s*m0;  ai[hi] = c*m1 - s*r0;
                }
            } else {
                int mask = 1 << p;
#pragma unroll
                for (int r = 0; r < 4; ++r) {
                    float pre = __shfl_xor(ar[r], mask);
                    float pim = __shfl_xor(ai[r], mask);
                    float nr = c*ar[r] + s*pim;
                    float ni = c*ai[r] - s*pre;
                    ar[r] = nr; ai[r] = ni;
                }
            }
        }
#pragma unroll
        for (int w = 0; w < NQ; ++w) {
            const float* p3 = qw + (l * NQ + w) * 3;
            float phi = p3[0], th = p3[1], om = p3[2];
            float ct = cosf(0.5f * th), st = sinf(0.5f * th);
            float al = 0.5f * (phi + om), be = 0.5f * (phi - om);
            float ca = cosf(al), sa = sinf(al), cb = cosf(be), sb = sinf(be);
            float u00r =  ct * ca, u00i = -ct * sa;
            float u01r = -st * cb, u01i = -st * sb;
            float u10r =  st * cb, u10i = -st * sb;
            float u11r =  ct * ca, u11i =  ct * sa;
            int p = 7 - w;
            if (p >= 6) {
#pragma unroll
                for (int pi_ = 0; pi_ < 2; ++pi_) {
                    int lo = (p == 7) ? pi_ : pi_ * 2;
                    int hi = (p == 7) ? pi_ + 2 : pi_ * 2 + 1;
                    float r0=ar[lo], m0=ai[lo], r1=ar[hi], m1=ai[hi];
                    ar[lo] = u00r*r0 - u00i*m0 + u01r*r1 - u01i*m1;
                    ai[lo] = u00r*m0 + u00i*r0 + u01r*m1 + u01i*r1;
                    ar[hi] = u10r*r0 - u10i*m0 + u11r*r1 - u11i*m1;
                    ai[hi] = u10r*m0 + u10i*r0 + u11r*m1 + u11i*r1;
                }
            } else {
                int mask = 1 << p;
                int bit = (L >> p) & 1;
                float car = bit ? u11r : u00r, cai = bit ? u11i : u00i;
                float cpr = bit ? u10r : u01r, cpi = bit ? u10i : u01i;
#pragma unroll
                for (int r = 0; r < 4; ++r) {
                    float pre = __shfl_xor(ar[r], mask);
                    float pim = __shfl_xor(ai[r], mask);
                    float nr = car*ar[r] - cai*ai[r] + cpr*pre - cpi*pim;
                    float ni = car*ai[r] + cai*ar[r] + cpr*pim + cpi*pre;
                    ar[r] = nr; ai[r] = ni;
                }
            }
        }
        { float t0=ar[2]; ar[2]=ar[3]; ar[3]=t0; t0=ai[2]; ai[2]=ai[3]; ai[3]=t0; }
        ar[1]=__shfl_xor(ar[1],32); ai[1]=__shfl_xor(ai[1],32);
        ar[3]=__shfl_xor(ar[3],32); ai[3]=__shfl_xor(ai[3],32);
#pragma unroll
        for (int w = 2; w <= 6; ++w) {
            int pc = 7 - w, pt = 6 - w;
            int tm = 1 << pt;
            bool ctrl = (L >> pc) & 1;
#pragma unroll
            for (int r = 0; r < 4; ++r) {
                float swr = __shfl_xor(ar[r], tm);
                float swi = __shfl_xor(ai[r], tm);
                ar[r] = ctrl ? swr : ar[r];
                ai[r] = ctrl ? swi : ai[r];
            }
        }
        {
            bool ctrl = L & 1;
            float n0r = ctrl ? ar[2] : ar[0], n2r = ctrl ? ar[0] : ar[2];
            float n0i = ctrl ? ai[2] : ai[0], n2i = ctrl ? ai[0] : ai[2];
            float n1r = ctrl ? ar[3] : ar[1], n3r = ctrl ? ar[1] : ar[3];
            float n1i = ctrl ? ai[3] : ai[1], n3i = ctrl ? ai[1] : ai[3];
            ar[0]=n0r; ar[1]=n1r; ar[2]=n2r; ar[3]=n3r;
            ai[0]=n0i; ai[1]=n1i; ai[2]=n2i; ai[3]=n3i;
        }
    }

    // ---- <Z_w>, w=0..2 ----
    {
        float p0 = ar[0]*ar[0]+ai[0]*ai[0];
        float p1 = ar[1]*ar[1]+ai[1]*ai[1];
        float p2 = ar[2]*ar[2]+ai[2]*ai[2];
        float p3 = ar[3]*ar[3]+ai[3]*ai[3];
        float z0 = p0 + p1 - p2 - p3;
        float z1 = p0 - p1 + p2 - p3;
        float zs = p0 + p1 + p2 + p3;
        float z2 = (L & 32) ? -zs : zs;
#pragma unroll
        for (int off = 1; off < 64; off <<= 1) {
            z0 += __shfl_xor(z0, off);
            z1 += __shfl_xor(z1, off);
            z2 += __shfl_xor(z2, off);
        }
        if (L == 0) {
            out[b * NC + 0] = z0;
            out[b * NC + 1] = z1;
            out[b * NC + 2] = z2;
        }
    }

    // ---- hand off psi through LDS, redistribute to column layout ----
#pragma unroll
    for (int r = 0; r < 4; ++r) Ps2[(r << 6) | L] = make_float2(ar[r], ai[r]);
    __syncthreads();
    int c   = L >> 2;                 // my column
    int seg = L & 3;                  // my segment (4 elements)
    float gr[4], gi[4];
#pragma unroll
    for (int j = 0; j < 4; ++j) {
        float2 t = Ps2[(seg * 4 + j) * 16 + c];
        gr[j] = t.x; gi[j] = t.y;
    }
    // initial column norm^2 (uniform across the quad)
    float alm = 0.f;
#pragma unroll
    for (int j = 0; j < 4; ++j) alm += gr[j]*gr[j] + gi[j]*gi[j];
    alm += __shfl_xor(alm, 1);
    alm += __shfl_xor(alm, 2);

    // ---- one-sided Jacobi: XOR tournament, shfl_xor exchange ----
    for (int sweep = 0; sweep < NSWEEP; ++sweep) {
#pragma unroll 1
        for (int m = 1; m <= 15; ++m) {
            int xm = m << 2;          // lane xor mask (column bits)
            float pgr[4], pgi[4];
#pragma unroll
            for (int j = 0; j < 4; ++j) {
                pgr[j] = __shfl_xor(gr[j], xm);
                pgi[j] = __shfl_xor(gi[j], xm);
            }
            float bep = __shfl_xor(alm, xm);   // partner norm (same latency group)
            float d = 0.f, e = 0.f;
#pragma unroll
            for (int j = 0; j < 4; ++j) {
                d += gr[j]*pgr[j] + gi[j]*pgi[j];   // Re(mine^H partner)
                e += gr[j]*pgi[j] - gi[j]*pgr[j];   // Im(mine^H partner)
            }
            d += __shfl_xor(d, 1); e += __shfl_xor(e, 1);
            d += __shfl_xor(d, 2); e += __shfl_xor(e, 2);
            float g2 = d*d + e*e;
            float cth = 1.f, sth = 0.f, cph = 1.f, sph = 0.f, gn = 0.f;
            if (g2 > 1e-26f) {
                gn = sqrtf(g2);
                float ginv = 1.f / gn;
                cph = d * ginv; sph = -e * ginv;    // conj(gamma)/|gamma|
                float tau = (alm - bep) * (0.5f * ginv);
                float t = ((tau >= 0.f) ? 1.f : -1.f) / (fabsf(tau) + sqrtf(1.f + tau*tau));
                cth = rsqrtf(1.f + t*t);
                sth = t * cth;
            }
#pragma unroll
            for (int j = 0; j < 4; ++j) {
                float er = cph*pgr[j] - sph*pgi[j];
                float ei = cph*pgi[j] + sph*pgr[j];
                gr[j] = cth * gr[j] + sth * er;
                gi[j] = cth * gi[j] + sth * ei;
            }
            // exact incremental norm: cross term is real = gn after phase fold
            alm = cth*cth*alm + sth*sth*bep + 2.f*cth*sth*gn;
        }
    }

    float ev = fminf(fmaxf(alm, 1e-10f), 1.0f);
    float term = -ev * logf(ev);
#pragma unroll
    for (int off = 4; off < 64; off <<= 1) term += __shfl_xor(term, off);
    if (L == 0) out[BB * NC + b] = term;
}

extern "C" void kernel_launch(void* const* d_in, const int* in_sizes, int n_in,
                              void* d_out, int out_size, void* d_ws, size_t ws_size,
                              hipStream_t stream) {
    const float* x    = (const float*)d_in[0];
    const float* Wemb = (const float*)d_in[1];
    const float* bemb = (const float*)d_in[2];
    const float* Wq   = (const float*)d_in[3];
    const float* bq   = (const float*)d_in[4];
    const float* Wk   = (const float*)d_in[5];
    const float* bk   = (const float*)d_in[6];
    const float* Wv   = (const float*)d_in[7];
    const float* bv   = (const float*)d_in[8];
    const float* Wo   = (const float*)d_in[9];
    const float* bo   = (const float*)d_in[10];
    const float* ln1g = (const float*)d_in[11];
    const float* ln1b = (const float*)d_in[12];
    const float* ln2g = (const float*)d_in[13];
    const float* ln2b = (const float*)d_in[14];
    const float* Wf1  = (const float*)d_in[15];
    const float* bf1  = (const float*)d_in[16];
    const float* Wf2  = (const float*)d_in[17];
    const float* bf2  = (const float*)d_in[18];
    const float* Wp1  = (const float*)d_in[19];
    const float* bp1  = (const float*)d_in[20];
    const float* Wp2  = (const float*)d_in[21];
    const float* bp2  = (const float*)d_in[22];
    const float* qwts = (const float*)d_in[23];
    float* out = (float*)d_out;

    const size_t M = 1u << 20;           // 1M floats = B*S*D
    auto needF = [&](int nch) {
        return (size_t)(4.5 * M) + (size_t)nch * M + (size_t)nch * BHS_TOT + BB * 8 * DD + 16384;
    };
    int nch = (ws_size >= needF(4) * sizeof(float)) ? 4 : 2;

    float* ws     = (float*)d_ws;
    float* h      = ws;                               // 1M
    hf2*   qh     = (hf2*)(ws + M);                   // 0.5M floats
    hf2*   kvh    = (hf2*)(ws + M + M / 2);           // 1M floats
    float* Apart  = ws + (M * 9) / 2;                 // nch*M
    float* lpart  = Apart + (size_t)nch * M;          // nch*BHS_TOT
    float* pp     = lpart + (size_t)nch * BHS_TOT;    // [16][8][64]

    k_embed<<<BB * SS, 64, 0, stream>>>(x, Wemb, bemb, h);
    for (int l = 0; l < NLAYER; ++l) {
        k_qkv<<<BB * SS / 4, 64, 0, stream>>>(h, Wq, bq, Wk, bk, Wv, bv, qh, kvh, l);
        k_attn<<<dim3(BB * HH, 4 * nch), 256, 0, stream>>>(qh, (const float4*)kvh, Apart, lpart, nch);
        k_projln<<<BB * SS / 4, 64, 0, stream>>>(Apart, lpart, Wo, bo, ln1g, ln1b, h, l, nch);
        k_ffn<<<BB * SS / 4, 128, 0, stream>>>(Wf1, bf1, Wf2, bf2, ln2g, ln2b, h, l);
    }
    k_pool<<<dim3(BB, 8), 64, 0, stream>>>(h, pp);
    k_tail<<<BB, 64, 0, stream>>>(pp, Wp1, bp1, Wp2, bp2, qwts, out);
}